// Round 1
// baseline (2287.250 us; speedup 1.0000x reference)
//
#include <hip/hip_runtime.h>
#include <math.h>

#define B_ 32
#define N_ 2048
#define D_ 512
#define BM 64
#define BN 128
#define BK 32
#define NT 256

// ---------------------------------------------------------------------------
// Kernel 1: fused flash-attention (Q=src_embed, K=tgt_embed, V=tgt) that
// directly accumulates the 15 per-block Kabsch partial sums:
//   [0..2]  sum_n src[n][c]
//   [3..5]  sum_n matched[c][n]
//   [6..14] sum_n src[n][c]*matched[d][n]   (index 6 + c*3 + d)
// Each block: one batch b, 64 src rows. 256 threads = 16x16 (ty=row/4, tx=col/8).
// ---------------------------------------------------------------------------
__global__ __launch_bounds__(NT) void attn_partial_kernel(
    const float* __restrict__ src,        // (B,N,3)
    const float* __restrict__ tgt,        // (B,N,3)
    const float* __restrict__ src_embed,  // (B,N,D)
    const float* __restrict__ tgt_embed,  // (B,N,D)
    double* __restrict__ partials)        // (1024, 15)
{
    __shared__ float Qs[BK][BM];     // 8 KB, k-major
    __shared__ float Ks[BK][BN];     // 16 KB, k-major
    __shared__ float Ts[BN][3];      // tgt coords for current chunk
    __shared__ double red[16][15];   // block reduction buffer

    const int blk = blockIdx.x;
    const int b   = blk >> 5;          // 32 row-blocks per batch
    const int n0  = (blk & 31) * BM;
    const int tid = threadIdx.x;
    const int ty  = tid >> 4;          // 0..15 -> rows 4*ty..4*ty+3
    const int tx  = tid & 15;          // 0..15 -> cols 8*tx..8*tx+7

    const float scale = 0.044194173824159216f;  // 1/sqrt(512), folded into Q

    const float* qbase = src_embed + ((size_t)b * N_ + n0) * D_;
    const float* kbase = tgt_embed + (size_t)b * N_ * D_;

    // online softmax state, per thread: 4 rows x (partial over this thread's 8 cols)
    float m_run[4], l_run[4], a0[4], a1[4], a2[4];
#pragma unroll
    for (int r = 0; r < 4; ++r) {
        m_run[r] = -1e30f; l_run[r] = 0.f; a0[r] = 0.f; a1[r] = 0.f; a2[r] = 0.f;
    }

    const int qrow = tid >> 3;   // 0..31 (staging row)
    const int qc4  = tid & 7;    // 0..7  (staging float4 col)

    for (int m0 = 0; m0 < N_; m0 += BN) {
        float s[4][8];
#pragma unroll
        for (int r = 0; r < 4; ++r)
#pragma unroll
            for (int c = 0; c < 8; ++c) s[r][c] = 0.f;

        for (int kk = 0; kk < D_; kk += BK) {
            __syncthreads();   // previous tile fully consumed
            // ---- stage Q tile (64 x 32), transposed to k-major, scale folded
#pragma unroll
            for (int i = 0; i < 2; ++i) {
                const int row = qrow + 32 * i;
                const float4 v = *reinterpret_cast<const float4*>(
                    qbase + (size_t)row * D_ + kk + qc4 * 4);
                Qs[qc4 * 4 + 0][row] = v.x * scale;
                Qs[qc4 * 4 + 1][row] = v.y * scale;
                Qs[qc4 * 4 + 2][row] = v.z * scale;
                Qs[qc4 * 4 + 3][row] = v.w * scale;
            }
            // ---- stage K tile (128 x 32), transposed to k-major
#pragma unroll
            for (int i = 0; i < 4; ++i) {
                const int row = qrow + 32 * i;
                const float4 v = *reinterpret_cast<const float4*>(
                    kbase + (size_t)(m0 + row) * D_ + kk + qc4 * 4);
                Ks[qc4 * 4 + 0][row] = v.x;
                Ks[qc4 * 4 + 1][row] = v.y;
                Ks[qc4 * 4 + 2][row] = v.z;
                Ks[qc4 * 4 + 3][row] = v.w;
            }
            // ---- stage tgt coords once per m-chunk
            if (kk == 0 && tid < BN) {
                const float* tp = tgt + ((size_t)b * N_ + m0 + tid) * 3;
                Ts[tid][0] = tp[0]; Ts[tid][1] = tp[1]; Ts[tid][2] = tp[2];
            }
            __syncthreads();
            // ---- 4x8 register-tile FMA over BK
#pragma unroll
            for (int k = 0; k < BK; ++k) {
                const float4 qv = *reinterpret_cast<const float4*>(&Qs[k][4 * ty]);
                const float4 ka = *reinterpret_cast<const float4*>(&Ks[k][8 * tx]);
                const float4 kb = *reinterpret_cast<const float4*>(&Ks[k][8 * tx + 4]);
                const float q[4]  = {qv.x, qv.y, qv.z, qv.w};
                const float kv[8] = {ka.x, ka.y, ka.z, ka.w, kb.x, kb.y, kb.z, kb.w};
#pragma unroll
                for (int r = 0; r < 4; ++r)
#pragma unroll
                    for (int c = 0; c < 8; ++c)
                        s[r][c] = fmaf(q[r], kv[c], s[r][c]);
            }
        }

        // ---- online softmax update for this 64x128 score tile
#pragma unroll
        for (int r = 0; r < 4; ++r) {
            float mx = s[r][0];
#pragma unroll
            for (int c = 1; c < 8; ++c) mx = fmaxf(mx, s[r][c]);
            // reduce max across the 16 threads sharing this row
            for (int off = 1; off < 16; off <<= 1)
                mx = fmaxf(mx, __shfl_xor(mx, off, 64));

            const float mnew = fmaxf(m_run[r], mx);
            const float corr = __expf(m_run[r] - mnew);
            l_run[r] *= corr; a0[r] *= corr; a1[r] *= corr; a2[r] *= corr;

            float ps = 0.f, p0 = 0.f, p1 = 0.f, p2 = 0.f;
#pragma unroll
            for (int c = 0; c < 8; ++c) {
                const float p = __expf(s[r][c] - mnew);
                const int m = 8 * tx + c;
                ps += p;
                p0 = fmaf(p, Ts[m][0], p0);
                p1 = fmaf(p, Ts[m][1], p1);
                p2 = fmaf(p, Ts[m][2], p2);
            }
            l_run[r] += ps; a0[r] += p0; a1[r] += p1; a2[r] += p2;
            m_run[r] = mnew;
        }
    }

    // ---- finalize rows: reduce (l, acc) across 16 tx-threads, form partials
    double loc[15];
#pragma unroll
    for (int i = 0; i < 15; ++i) loc[i] = 0.0;

#pragma unroll
    for (int r = 0; r < 4; ++r) {
        float l = l_run[r], b0 = a0[r], b1 = a1[r], b2 = a2[r];
        for (int off = 1; off < 16; off <<= 1) {
            l  += __shfl_xor(l,  off, 64);
            b0 += __shfl_xor(b0, off, 64);
            b1 += __shfl_xor(b1, off, 64);
            b2 += __shfl_xor(b2, off, 64);
        }
        if (tx == 0) {
            const float inv = 1.0f / l;
            const double mx0 = (double)(b0 * inv);
            const double mx1 = (double)(b1 * inv);
            const double mx2 = (double)(b2 * inv);
            const int n = n0 + 4 * ty + r;
            const float* sp = src + ((size_t)b * N_ + n) * 3;
            const double s0 = sp[0], s1 = sp[1], s2 = sp[2];
            loc[0] += s0;  loc[1] += s1;  loc[2] += s2;
            loc[3] += mx0; loc[4] += mx1; loc[5] += mx2;
            loc[6]  += s0 * mx0; loc[7]  += s0 * mx1; loc[8]  += s0 * mx2;
            loc[9]  += s1 * mx0; loc[10] += s1 * mx1; loc[11] += s1 * mx2;
            loc[12] += s2 * mx0; loc[13] += s2 * mx1; loc[14] += s2 * mx2;
        }
    }

    __syncthreads();
    if (tx == 0) {
#pragma unroll
        for (int i = 0; i < 15; ++i) red[ty][i] = loc[i];
    }
    __syncthreads();
    if (tid < 15) {
        double sum = 0.0;
        for (int j = 0; j < 16; ++j) sum += red[j][tid];
        partials[(size_t)blk * 15 + tid] = sum;
    }
}

// ---------------------------------------------------------------------------
// Kernel 2: per-batch reduce of 32 partial blocks + Kabsch (fp64, 1 thr/batch)
// R = V * diag(1/sigma) * V^T * H^T  (= V U^T from SVD of H), det-flip row 3.
// ---------------------------------------------------------------------------
__global__ void kabsch_kernel(const double* __restrict__ partials,
                              float* __restrict__ out)
{
    const int b = threadIdx.x;
    if (b >= B_) return;

    double acc[15];
#pragma unroll
    for (int i = 0; i < 15; ++i) acc[i] = 0.0;
    for (int rb = 0; rb < 32; ++rb) {
        const double* p = partials + ((size_t)b * 32 + rb) * 15;
#pragma unroll
        for (int i = 0; i < 15; ++i) acc[i] += p[i];
    }

    const double invN = 1.0 / (double)N_;
    const double S[3] = {acc[0], acc[1], acc[2]};
    const double M[3] = {acc[3], acc[4], acc[5]};
    double H[3][3];
    for (int c = 0; c < 3; ++c)
        for (int d = 0; d < 3; ++d)
            H[c][d] = acc[6 + c * 3 + d] - S[c] * M[d] * invN;

    // A = H^T H (symmetric PSD)
    double A[3][3];
    for (int i = 0; i < 3; ++i)
        for (int j = 0; j < 3; ++j)
            A[i][j] = H[0][i] * H[0][j] + H[1][i] * H[1][j] + H[2][i] * H[2][j];

    double V[3][3] = {{1, 0, 0}, {0, 1, 0}, {0, 0, 1}};
    const int PQ[3][2] = {{0, 1}, {0, 2}, {1, 2}};
    for (int sweep = 0; sweep < 20; ++sweep) {
        const double off = fabs(A[0][1]) + fabs(A[0][2]) + fabs(A[1][2]);
        if (off < 1e-24) break;
        for (int pi = 0; pi < 3; ++pi) {
            const int p = PQ[pi][0], q = PQ[pi][1], rr = 3 - p - q;
            const double apq = A[p][q];
            if (fabs(apq) < 1e-300) continue;
            const double theta = (A[q][q] - A[p][p]) / (2.0 * apq);
            const double tt = (theta >= 0.0 ? 1.0 : -1.0) /
                              (fabs(theta) + sqrt(1.0 + theta * theta));
            const double c = 1.0 / sqrt(1.0 + tt * tt);
            const double sn = tt * c;
            const double app = A[p][p], aqq = A[q][q];
            const double arp = A[rr][p], arq = A[rr][q];
            A[p][p] = app - tt * apq;
            A[q][q] = aqq + tt * apq;
            A[p][q] = A[q][p] = 0.0;
            A[rr][p] = A[p][rr] = c * arp - sn * arq;
            A[rr][q] = A[q][rr] = sn * arp + c * arq;
            for (int k = 0; k < 3; ++k) {
                const double vkp = V[k][p], vkq = V[k][q];
                V[k][p] = c * vkp - sn * vkq;
                V[k][q] = sn * vkp + c * vkq;
            }
        }
    }

    // R = sum_i v_i (H v_i)^T / sigma_i
    double R[3][3] = {{0, 0, 0}, {0, 0, 0}, {0, 0, 0}};
    for (int i = 0; i < 3; ++i) {
        const double lam = A[i][i];
        const double sig = sqrt(lam > 0.0 ? lam : 0.0);
        const double inv = 1.0 / (sig > 1e-30 ? sig : 1e-30);
        double w[3];
        for (int c = 0; c < 3; ++c)
            w[c] = H[c][0] * V[0][i] + H[c][1] * V[1][i] + H[c][2] * V[2][i];
        for (int r = 0; r < 3; ++r)
            for (int c = 0; c < 3; ++c)
                R[r][c] += V[r][i] * w[c] * inv;
    }

    const double det =
        R[0][0] * (R[1][1] * R[2][2] - R[1][2] * R[2][1]) -
        R[0][1] * (R[1][0] * R[2][2] - R[1][2] * R[2][0]) +
        R[0][2] * (R[1][0] * R[2][1] - R[1][1] * R[2][0]);
    if (det < 0.0) {
        R[2][0] = -R[2][0]; R[2][1] = -R[2][1]; R[2][2] = -R[2][2];
    }

    // t = -R * src_cent + matched_cent
    double t[3];
    for (int c = 0; c < 3; ++c)
        t[c] = M[c] * invN -
               (R[c][0] * S[0] + R[c][1] * S[1] + R[c][2] * S[2]) * invN;

    for (int r = 0; r < 3; ++r)
        for (int c = 0; c < 3; ++c)
            out[(size_t)b * 9 + r * 3 + c] = (float)R[r][c];
    for (int c = 0; c < 3; ++c)
        out[(size_t)B_ * 9 + (size_t)b * 3 + c] = (float)t[c];
}

// ---------------------------------------------------------------------------
extern "C" void kernel_launch(void* const* d_in, const int* in_sizes, int n_in,
                              void* d_out, int out_size, void* d_ws, size_t ws_size,
                              hipStream_t stream) {
    const float* src = (const float*)d_in[0];
    const float* tgt = (const float*)d_in[1];
    const float* se  = (const float*)d_in[2];
    const float* te  = (const float*)d_in[3];
    float* out = (float*)d_out;
    double* partials = (double*)d_ws;   // needs 1024*15*8 = 122880 bytes

    attn_partial_kernel<<<dim3(B_ * (N_ / BM)), dim3(NT), 0, stream>>>(
        src, tgt, se, te, partials);
    kabsch_kernel<<<dim3(1), dim3(64), 0, stream>>>(partials, out);
}

// Round 2
// 821.475 us; speedup vs baseline: 2.7843x; 2.7843x over previous
//
#include <hip/hip_runtime.h>
#include <math.h>

#define B_ 32
#define N_ 2048
#define D_ 512
#define BM 64      // Q rows per block (4 waves x 16)
#define BN 128     // KV chunk
#define NT 256

typedef __attribute__((ext_vector_type(8))) short s16x8;   // 8 bf16
typedef __attribute__((ext_vector_type(4))) float f32x4;

__device__ inline unsigned f2bf(float x) {
    unsigned u = __float_as_uint(x);
    return (u + 0x7FFFu + ((u >> 16) & 1u)) >> 16;   // RNE
}
__device__ inline float bf2f(unsigned h) { return __uint_as_float(h << 16); }

// ---------------------------------------------------------------------------
// Fused flash attention (Q=src_embed, K=tgt_embed, V=tgt) on bf16 MFMA with
// hi/lo split (S = Qhi Khi + Qlo Khi + Qhi Klo), accumulating 15 Kabsch
// partials per block. Swapped operands: mfma(A=K, B=Q) so D[n][m] has
// col=m=lane&15 -> each lane owns ONE q-row; softmax reduce = 2 shuffles.
// ---------------------------------------------------------------------------
__global__ __launch_bounds__(NT, 2) void attn_partial_kernel(
    const float* __restrict__ src,
    const float* __restrict__ tgt,
    const float* __restrict__ src_embed,
    const float* __restrict__ tgt_embed,
    double* __restrict__ partials)
{
    __shared__ short Khi_s[BN * 64];   // 16 KB, XOR-swizzled row-major [128][64]
    __shared__ short Klo_s[BN * 64];   // 16 KB
    __shared__ float4 Ts4[BN];         // 2 KB tgt coords
    __shared__ double red[BM][15];     // 7.7 KB

    char* KhiB = (char*)Khi_s;
    char* KloB = (char*)Klo_s;

    // XCD-aware mapping: batch b entirely on one XCD (K panel L2-resident)
    const int w    = blockIdx.x;
    const int xcd  = w & 7;
    const int idx  = w >> 3;            // 0..127
    const int b    = xcd * 4 + (idx >> 5);
    const int n0   = (idx & 31) * BM;
    const int blk  = b * 32 + (idx & 31);   // partials slot (batch-major)

    const int tid  = threadIdx.x;
    const int wv   = tid >> 6;
    const int lane = tid & 63;
    const int lr   = lane & 15;         // q-row within wave / K row within frag
    const int lg   = lane >> 4;         // 0..3
    const unsigned swl = (unsigned)((lr & 7) << 4);

    const float scale = 0.044194173824159216f;  // 1/sqrt(512)

    const float* kbase = tgt_embed + (size_t)b * N_ * D_;

    // ---- load this lane's Q row (hi/lo bf16 fragments, scale folded) -------
    const int qrow = n0 + wv * 16 + lr;
    const float* qp = src_embed + ((size_t)b * N_ + qrow) * D_ + lg * 8;
    s16x8 qhi[16], qlo[16];
#pragma unroll
    for (int s = 0; s < 16; ++s) {
        const float4 f0 = *reinterpret_cast<const float4*>(qp + s * 32);
        const float4 f1 = *reinterpret_cast<const float4*>(qp + s * 32 + 4);
        const float x[8] = {f0.x, f0.y, f0.z, f0.w, f1.x, f1.y, f1.z, f1.w};
#pragma unroll
        for (int i = 0; i < 8; ++i) {
            const float v = x[i] * scale;
            const unsigned h = f2bf(v);
            qhi[s][i] = (short)h;
            qlo[s][i] = (short)f2bf(v - bf2f(h));
        }
    }

    // online softmax state: this lane's q-row, partial over its n-subset
    float m_run = -1e30f, l_run = 0.f, a0 = 0.f, a1 = 0.f, a2 = 0.f;

    const int srow = tid >> 1;      // staging: 128 rows x 2 halves
    const int shalf = tid & 1;
    const unsigned swr = (unsigned)((srow & 7) << 4);

    for (int m0 = 0; m0 < N_; m0 += BN) {
        f32x4 acc[8];
#pragma unroll
        for (int nf = 0; nf < 8; ++nf) acc[nf] = (f32x4){0.f, 0.f, 0.f, 0.f};

#pragma unroll
        for (int kt = 0; kt < 8; ++kt) {
            __syncthreads();   // previous tile / Ts fully consumed
            // ---- stage K tile [128 rows][64 k] as bf16 hi/lo, swizzled ----
            {
                const float* gp = kbase + (size_t)(m0 + srow) * D_ + kt * 64 + shalf * 32;
#pragma unroll
                for (int grp = 0; grp < 4; ++grp) {
                    const float4 fa = *reinterpret_cast<const float4*>(gp + grp * 8);
                    const float4 fb = *reinterpret_cast<const float4*>(gp + grp * 8 + 4);
                    const float x[8] = {fa.x, fa.y, fa.z, fa.w, fb.x, fb.y, fb.z, fb.w};
                    s16x8 hi, lo;
#pragma unroll
                    for (int i = 0; i < 8; ++i) {
                        const unsigned h = f2bf(x[i]);
                        hi[i] = (short)h;
                        lo[i] = (short)f2bf(x[i] - bf2f(h));
                    }
                    const unsigned off = (unsigned)srow * 128u +
                        (((unsigned)(shalf * 64 + grp * 16)) ^ swr);
                    *reinterpret_cast<s16x8*>(KhiB + off) = hi;
                    *reinterpret_cast<s16x8*>(KloB + off) = lo;
                }
                if (kt == 0 && tid < BN) {
                    const float* tp = tgt + ((size_t)b * N_ + m0 + tid) * 3;
                    Ts4[tid] = make_float4(tp[0], tp[1], tp[2], 0.f);
                }
            }
            __syncthreads();
            // ---- MFMA: 2 k-substeps x 8 n-frags x 3 products --------------
#pragma unroll
            for (int ks = 0; ks < 2; ++ks) {
                const int s = kt * 2 + ks;
                const unsigned kb = ((unsigned)(lg * 16 + ks * 64)) ^ swl;
#pragma unroll
                for (int nf = 0; nf < 8; ++nf) {
                    const unsigned off = (unsigned)(nf * 16 + lr) * 128u + kb;
                    const s16x8 ah = *reinterpret_cast<const s16x8*>(KhiB + off);
                    const s16x8 al = *reinterpret_cast<const s16x8*>(KloB + off);
                    acc[nf] = __builtin_amdgcn_mfma_f32_16x16x32_bf16(ah, qhi[s], acc[nf], 0, 0, 0);
                    acc[nf] = __builtin_amdgcn_mfma_f32_16x16x32_bf16(al, qhi[s], acc[nf], 0, 0, 0);
                    acc[nf] = __builtin_amdgcn_mfma_f32_16x16x32_bf16(ah, qlo[s], acc[nf], 0, 0, 0);
                }
            }
        }

        // ---- online softmax + PV epilogue (scores lane-local) -------------
        float mx = -1e30f;
#pragma unroll
        for (int nf = 0; nf < 8; ++nf)
#pragma unroll
            for (int r = 0; r < 4; ++r) mx = fmaxf(mx, acc[nf][r]);
        mx = fmaxf(mx, __shfl_xor(mx, 16));
        mx = fmaxf(mx, __shfl_xor(mx, 32));

        const float mnew = fmaxf(m_run, mx);
        const float corr = __expf(m_run - mnew);
        l_run *= corr; a0 *= corr; a1 *= corr; a2 *= corr;

        float ps = 0.f, p0 = 0.f, p1 = 0.f, p2 = 0.f;
#pragma unroll
        for (int nf = 0; nf < 8; ++nf)
#pragma unroll
            for (int r = 0; r < 4; ++r) {
                const float p = __expf(acc[nf][r] - mnew);
                const int n = nf * 16 + lg * 4 + r;
                const float4 tv = Ts4[n];
                ps += p;
                p0 = fmaf(p, tv.x, p0);
                p1 = fmaf(p, tv.y, p1);
                p2 = fmaf(p, tv.z, p2);
            }
        l_run += ps; a0 += p0; a1 += p1; a2 += p2;
        m_run = mnew;
    }

    // ---- reduce the 4 lane-replicas of each q-row -------------------------
    l_run += __shfl_xor(l_run, 16); l_run += __shfl_xor(l_run, 32);
    a0 += __shfl_xor(a0, 16); a0 += __shfl_xor(a0, 32);
    a1 += __shfl_xor(a1, 16); a1 += __shfl_xor(a1, 32);
    a2 += __shfl_xor(a2, 16); a2 += __shfl_xor(a2, 32);

    __syncthreads();   // Ts4 reads done; red[] reuse safe
    if (lg == 0) {
        const double inv = 1.0 / (double)l_run;
        const double mx0 = (double)a0 * inv;
        const double mx1 = (double)a1 * inv;
        const double mx2 = (double)a2 * inv;
        const float* sp = src + ((size_t)b * N_ + qrow) * 3;
        const double s0 = sp[0], s1 = sp[1], s2 = sp[2];
        double* rp = red[wv * 16 + lr];
        rp[0] = s0;  rp[1] = s1;  rp[2] = s2;
        rp[3] = mx0; rp[4] = mx1; rp[5] = mx2;
        rp[6]  = s0 * mx0; rp[7]  = s0 * mx1; rp[8]  = s0 * mx2;
        rp[9]  = s1 * mx0; rp[10] = s1 * mx1; rp[11] = s1 * mx2;
        rp[12] = s2 * mx0; rp[13] = s2 * mx1; rp[14] = s2 * mx2;
    }
    __syncthreads();
    if (tid < 15) {
        double sum = 0.0;
        for (int r = 0; r < BM; ++r) sum += red[r][tid];
        partials[(size_t)blk * 15 + tid] = sum;
    }
}

// ---------------------------------------------------------------------------
// Kernel 2: per-batch reduce + Kabsch (fp64), unchanged from round 0 (passed)
// ---------------------------------------------------------------------------
__global__ void kabsch_kernel(const double* __restrict__ partials,
                              float* __restrict__ out)
{
    const int b = threadIdx.x;
    if (b >= B_) return;

    double acc[15];
#pragma unroll
    for (int i = 0; i < 15; ++i) acc[i] = 0.0;
    for (int rb = 0; rb < 32; ++rb) {
        const double* p = partials + ((size_t)b * 32 + rb) * 15;
#pragma unroll
        for (int i = 0; i < 15; ++i) acc[i] += p[i];
    }

    const double invN = 1.0 / (double)N_;
    const double S[3] = {acc[0], acc[1], acc[2]};
    const double M[3] = {acc[3], acc[4], acc[5]};
    double H[3][3];
    for (int c = 0; c < 3; ++c)
        for (int d = 0; d < 3; ++d)
            H[c][d] = acc[6 + c * 3 + d] - S[c] * M[d] * invN;

    double A[3][3];
    for (int i = 0; i < 3; ++i)
        for (int j = 0; j < 3; ++j)
            A[i][j] = H[0][i] * H[0][j] + H[1][i] * H[1][j] + H[2][i] * H[2][j];

    double V[3][3] = {{1, 0, 0}, {0, 1, 0}, {0, 0, 1}};
    const int PQ[3][2] = {{0, 1}, {0, 2}, {1, 2}};
    for (int sweep = 0; sweep < 20; ++sweep) {
        const double off = fabs(A[0][1]) + fabs(A[0][2]) + fabs(A[1][2]);
        if (off < 1e-24) break;
        for (int pi = 0; pi < 3; ++pi) {
            const int p = PQ[pi][0], q = PQ[pi][1], rr = 3 - p - q;
            const double apq = A[p][q];
            if (fabs(apq) < 1e-300) continue;
            const double theta = (A[q][q] - A[p][p]) / (2.0 * apq);
            const double tt = (theta >= 0.0 ? 1.0 : -1.0) /
                              (fabs(theta) + sqrt(1.0 + theta * theta));
            const double c = 1.0 / sqrt(1.0 + tt * tt);
            const double sn = tt * c;
            const double app = A[p][p], aqq = A[q][q];
            const double arp = A[rr][p], arq = A[rr][q];
            A[p][p] = app - tt * apq;
            A[q][q] = aqq + tt * apq;
            A[p][q] = A[q][p] = 0.0;
            A[rr][p] = A[p][rr] = c * arp - sn * arq;
            A[rr][q] = A[q][rr] = sn * arp + c * arq;
            for (int k = 0; k < 3; ++k) {
                const double vkp = V[k][p], vkq = V[k][q];
                V[k][p] = c * vkp - sn * vkq;
                V[k][q] = sn * vkp + c * vkq;
            }
        }
    }

    double R[3][3] = {{0, 0, 0}, {0, 0, 0}, {0, 0, 0}};
    for (int i = 0; i < 3; ++i) {
        const double lam = A[i][i];
        const double sig = sqrt(lam > 0.0 ? lam : 0.0);
        const double inv = 1.0 / (sig > 1e-30 ? sig : 1e-30);
        double wv[3];
        for (int c = 0; c < 3; ++c)
            wv[c] = H[c][0] * V[0][i] + H[c][1] * V[1][i] + H[c][2] * V[2][i];
        for (int r = 0; r < 3; ++r)
            for (int c = 0; c < 3; ++c)
                R[r][c] += V[r][i] * wv[c] * inv;
    }

    const double det =
        R[0][0] * (R[1][1] * R[2][2] - R[1][2] * R[2][1]) -
        R[0][1] * (R[1][0] * R[2][2] - R[1][2] * R[2][0]) +
        R[0][2] * (R[1][0] * R[2][1] - R[1][1] * R[2][0]);
    if (det < 0.0) {
        R[2][0] = -R[2][0]; R[2][1] = -R[2][1]; R[2][2] = -R[2][2];
    }

    double t[3];
    for (int c = 0; c < 3; ++c)
        t[c] = M[c] * invN -
               (R[c][0] * S[0] + R[c][1] * S[1] + R[c][2] * S[2]) * invN;

    for (int r = 0; r < 3; ++r)
        for (int c = 0; c < 3; ++c)
            out[(size_t)b * 9 + r * 3 + c] = (float)R[r][c];
    for (int c = 0; c < 3; ++c)
        out[(size_t)B_ * 9 + (size_t)b * 3 + c] = (float)t[c];
}

// ---------------------------------------------------------------------------
extern "C" void kernel_launch(void* const* d_in, const int* in_sizes, int n_in,
                              void* d_out, int out_size, void* d_ws, size_t ws_size,
                              hipStream_t stream) {
    const float* src = (const float*)d_in[0];
    const float* tgt = (const float*)d_in[1];
    const float* se  = (const float*)d_in[2];
    const float* te  = (const float*)d_in[3];
    float* out = (float*)d_out;
    double* partials = (double*)d_ws;   // 1024*15*8 = 122880 bytes

    attn_partial_kernel<<<dim3(B_ * (N_ / BM)), dim3(NT), 0, stream>>>(
        src, tgt, se, te, partials);
    kabsch_kernel<<<dim3(1), dim3(64), 0, stream>>>(partials, out);
}

// Round 3
// 267.146 us; speedup vs baseline: 8.5618x; 3.0750x over previous
//
#include <hip/hip_runtime.h>
#include <hip/hip_fp16.h>
#include <math.h>

#define B_ 32
#define N_ 2048
#define D_ 512
#define BN 128
#define NWAVE 8

typedef __attribute__((ext_vector_type(8))) _Float16 f16x8;
typedef __attribute__((ext_vector_type(8))) short s16x8;
typedef __attribute__((ext_vector_type(4))) float f32x4;
typedef __attribute__((ext_vector_type(4))) unsigned int u32x4;

__device__ inline unsigned packh2(float lo, float hi) {
    __half l = __float2half_rn(lo), h = __float2half_rn(hi);
    return (unsigned)__half_as_ushort(l) | ((unsigned)__half_as_ushort(h) << 16);
}
// bf16 helpers (fallback path)
__device__ inline unsigned f2bf(float x) {
    unsigned u = __float_as_uint(x);
    return (u + 0x7FFFu + ((u >> 16) & 1u)) >> 16;
}
__device__ inline float bf2f(unsigned h) { return __uint_as_float(h << 16); }

// ---------------------------------------------------------------------------
// Pre-pass: tgt_embed fp32 -> fp16, laid out as [b][mt(16)][kt(16)] tiles of
// 8KB, each tile pre-swizzled in LDS order: tile byte (r*64 + s*16) holds
// K[row=r][k = kt*32 + (s ^ ((r>>1)&3))*8 .. +8].
// ---------------------------------------------------------------------------
__global__ __launch_bounds__(256) void prepass_kernel(
    const float* __restrict__ te, u32x4* __restrict__ kp)
{
    const int idx = blockIdx.x * 256 + threadIdx.x;   // 0 .. 4194303
    const int b   = idx >> 17;
    const int r17 = idx & 131071;
    const int mt  = r17 >> 13;
    const int kt  = (r17 >> 9) & 15;
    const int o16 = r17 & 511;
    const int r   = o16 >> 2;
    const int s   = o16 & 3;
    const int lg  = s ^ ((r >> 1) & 3);
    const float* src = te + (((size_t)b * N_ + mt * 128 + r) * D_ + kt * 32 + lg * 8);
    const float4 f0 = *(const float4*)src;
    const float4 f1 = *(const float4*)(src + 4);
    u32x4 u;
    u[0] = packh2(f0.x, f0.y);
    u[1] = packh2(f0.z, f0.w);
    u[2] = packh2(f1.x, f1.y);
    u[3] = packh2(f1.z, f1.w);
    kp[idx] = u;
}

// ---------------------------------------------------------------------------
// Fast attention kernel: 256 blocks x 512 threads (8 waves). Block owns 256
// q-rows; wave owns 32 (2 B-frags). Q fp16 in registers (scale*log2e folded);
// K staged per 32-k phase from the pre-swizzled plane via global_load_lds
// into a double-buffered 8KB LDS tile. mfma(A=K, B=Q): lane owns q-row lr.
// ---------------------------------------------------------------------------
__global__ __launch_bounds__(512, 2) void attn_fast_kernel(
    const float* __restrict__ src, const float* __restrict__ tgt,
    const float* __restrict__ src_embed, const u32x4* __restrict__ kp,
    double* __restrict__ partials)
{
    __shared__ f16x8 Kbuf[2][512];       // 2 x 8KB
    __shared__ float4 TsB[2][BN];        // 4KB (double-buffered tgt coords)
    __shared__ double red[NWAVE][15];

    const int tid  = threadIdx.x;
    const int wv   = tid >> 6;
    const int lane = tid & 63;
    const int lr   = lane & 15;
    const int lg   = lane >> 4;

    const int xcd  = blockIdx.x & 7;
    const int slot = blockIdx.x >> 3;
    const int b    = xcd * 4 + (slot >> 3);   // 4 batches per XCD
    const int msl  = slot & 7;
    const int n0   = msl * 256;
    const int pblk = b * 8 + msl;

    const int sx   = lg ^ ((lr >> 1) & 3);    // swizzled 16B slot for frag reads
    char* KbufB = (char*)&Kbuf[0][0];

    // ---- Q: 2 frags x 16 k-chunks, fp16, (1/sqrt(512))*log2(e) folded ------
    const float QSC = 0.044194173824159216f * 1.4426950408889634f;
    f16x8 Qr[2][16];
#pragma unroll
    for (int qf = 0; qf < 2; ++qf) {
        const int qrow = n0 + wv * 32 + qf * 16 + lr;
        const float* qp = src_embed + ((size_t)b * N_ + qrow) * D_ + lg * 8;
#pragma unroll
        for (int s = 0; s < 16; ++s) {
            const float4 f0 = *(const float4*)(qp + s * 32);
            const float4 f1 = *(const float4*)(qp + s * 32 + 4);
            u32x4 u;
            u[0] = packh2(f0.x * QSC, f0.y * QSC);
            u[1] = packh2(f0.z * QSC, f0.w * QSC);
            u[2] = packh2(f1.x * QSC, f1.y * QSC);
            u[3] = packh2(f1.z * QSC, f1.w * QSC);
            Qr[qf][s] = __builtin_bit_cast(f16x8, u);
        }
    }

#define TILEPTR(mt_, kt_) (kp + ((((size_t)b * 16 + (mt_)) * 16 + (kt_)) << 9) + tid)
#define STAGE(mt_, kt_, bufi_) \
    __builtin_amdgcn_global_load_lds( \
        (const __attribute__((address_space(1))) void*)TILEPTR(mt_, kt_), \
        (__attribute__((address_space(3))) void*)(&Kbuf[bufi_][wv * 64]), 16, 0, 0)

    float m_s[2] = {-1e30f, -1e30f}, l_s[2] = {0.f, 0.f};
    float axs[2] = {0.f, 0.f}, ays[2] = {0.f, 0.f}, azs[2] = {0.f, 0.f};

    // prologue: tile (0,0) -> buf0, Ts for mc=0
    STAGE(0, 0, 0);
    if (tid < BN) {
        const float* tp = tgt + ((size_t)b * N_ + tid) * 3;
        TsB[0][tid] = make_float4(tp[0], tp[1], tp[2], 0.f);
    }
    __syncthreads();

    for (int mc = 0; mc < 16; ++mc) {
        f32x4 acc[2][8];
#pragma unroll
        for (int qf = 0; qf < 2; ++qf)
#pragma unroll
            for (int nf = 0; nf < 8; ++nf) acc[qf][nf] = (f32x4){0.f, 0.f, 0.f, 0.f};

        float tv0 = 0.f, tv1 = 0.f, tv2 = 0.f;
#pragma unroll
        for (int kt = 0; kt < 16; ++kt) {
            const int cur = kt & 1;
            if (kt < 15)          { STAGE(mc,     kt + 1, cur ^ 1); }
            else if (mc < 15)     { STAGE(mc + 1, 0,      cur ^ 1); }
            if (kt == 0 && mc < 15 && tid < BN) {
                const float* tp = tgt + ((size_t)b * N_ + (mc + 1) * BN + tid) * 3;
                tv0 = tp[0]; tv1 = tp[1]; tv2 = tp[2];
            }
            const char* base = KbufB + cur * 8192 + lr * 64 + sx * 16;
#pragma unroll
            for (int nf = 0; nf < 8; ++nf) {
                const f16x8 a = *(const f16x8*)(base + nf * 1024);
                acc[0][nf] = __builtin_amdgcn_mfma_f32_16x16x32_f16(a, Qr[0][kt], acc[0][nf], 0, 0, 0);
                acc[1][nf] = __builtin_amdgcn_mfma_f32_16x16x32_f16(a, Qr[1][kt], acc[1][nf], 0, 0, 0);
            }
            if (kt == 0 && mc < 15 && tid < BN)
                TsB[(mc + 1) & 1][tid] = make_float4(tv0, tv1, tv2, 0.f);
            __syncthreads();
        }

        // ---- online-softmax epilogue for this 128-wide chunk (log2 domain)
        const float4* Ts = TsB[mc & 1];
        float mx0 = -1e30f, mx1 = -1e30f;
#pragma unroll
        for (int nf = 0; nf < 8; ++nf)
#pragma unroll
            for (int r4 = 0; r4 < 4; ++r4) {
                mx0 = fmaxf(mx0, acc[0][nf][r4]);
                mx1 = fmaxf(mx1, acc[1][nf][r4]);
            }
        mx0 = fmaxf(mx0, __shfl_xor(mx0, 16)); mx0 = fmaxf(mx0, __shfl_xor(mx0, 32));
        mx1 = fmaxf(mx1, __shfl_xor(mx1, 16)); mx1 = fmaxf(mx1, __shfl_xor(mx1, 32));
        const float mn0 = fmaxf(m_s[0], mx0), mn1 = fmaxf(m_s[1], mx1);
        const float c0 = exp2f(m_s[0] - mn0), c1 = exp2f(m_s[1] - mn1);
        l_s[0] *= c0; axs[0] *= c0; ays[0] *= c0; azs[0] *= c0; m_s[0] = mn0;
        l_s[1] *= c1; axs[1] *= c1; ays[1] *= c1; azs[1] *= c1; m_s[1] = mn1;
        float l0 = 0.f, x0 = 0.f, y0 = 0.f, z0 = 0.f;
        float l1 = 0.f, x1 = 0.f, y1 = 0.f, z1 = 0.f;
#pragma unroll
        for (int nf = 0; nf < 8; ++nf)
#pragma unroll
            for (int r4 = 0; r4 < 4; ++r4) {
                const float4 tv = Ts[nf * 16 + lg * 4 + r4];
                const float p0 = exp2f(acc[0][nf][r4] - mn0);
                const float p1 = exp2f(acc[1][nf][r4] - mn1);
                l0 += p0; x0 = fmaf(p0, tv.x, x0); y0 = fmaf(p0, tv.y, y0); z0 = fmaf(p0, tv.z, z0);
                l1 += p1; x1 = fmaf(p1, tv.x, x1); y1 = fmaf(p1, tv.y, y1); z1 = fmaf(p1, tv.z, z1);
            }
        l_s[0] += l0; axs[0] += x0; ays[0] += y0; azs[0] += z0;
        l_s[1] += l1; axs[1] += x1; ays[1] += y1; azs[1] += z1;
        __syncthreads();   // protect TsB buffer reuse across waves
    }

    // ---- finalize: reduce lane-replicas, form per-block 15 partials --------
    double dl[15];
#pragma unroll
    for (int i = 0; i < 15; ++i) dl[i] = 0.0;
#pragma unroll
    for (int qf = 0; qf < 2; ++qf) {
        float lt = l_s[qf], x = axs[qf], y = ays[qf], z = azs[qf];
        lt += __shfl_xor(lt, 16); lt += __shfl_xor(lt, 32);
        x  += __shfl_xor(x, 16);  x  += __shfl_xor(x, 32);
        y  += __shfl_xor(y, 16);  y  += __shfl_xor(y, 32);
        z  += __shfl_xor(z, 16);  z  += __shfl_xor(z, 32);
        if (lg == 0) {
            const int qrow = n0 + wv * 32 + qf * 16 + lr;
            const float* sp = src + ((size_t)b * N_ + qrow) * 3;
            const double inv = 1.0 / (double)lt;
            const double m0d = (double)x * inv, m1d = (double)y * inv, m2d = (double)z * inv;
            const double s0 = sp[0], s1 = sp[1], s2 = sp[2];
            dl[0] += s0;  dl[1] += s1;  dl[2] += s2;
            dl[3] += m0d; dl[4] += m1d; dl[5] += m2d;
            dl[6]  += s0 * m0d; dl[7]  += s0 * m1d; dl[8]  += s0 * m2d;
            dl[9]  += s1 * m0d; dl[10] += s1 * m1d; dl[11] += s1 * m2d;
            dl[12] += s2 * m0d; dl[13] += s2 * m1d; dl[14] += s2 * m2d;
        }
    }
#pragma unroll
    for (int i = 0; i < 15; ++i) {
        double v = dl[i];
        for (int off = 1; off < 64; off <<= 1) v += __shfl_xor(v, off);
        dl[i] = v;
    }
    if (lane == 0) {
#pragma unroll
        for (int i = 0; i < 15; ++i) red[wv][i] = dl[i];
    }
    __syncthreads();
    if (tid < 15) {
        double sum = 0.0;
        for (int w = 0; w < NWAVE; ++w) sum += red[w][tid];
        partials[(size_t)pblk * 15 + tid] = sum;
    }
#undef STAGE
#undef TILEPTR
}

// ---------------------------------------------------------------------------
// Fallback (proven round-2 kernel): bf16 hi/lo 3-product, 1024 blocks.
// ---------------------------------------------------------------------------
__global__ __launch_bounds__(256, 2) void attn_v2_kernel(
    const float* __restrict__ src, const float* __restrict__ tgt,
    const float* __restrict__ src_embed, const float* __restrict__ tgt_embed,
    double* __restrict__ partials)
{
    __shared__ short Khi_s[128 * 64];
    __shared__ short Klo_s[128 * 64];
    __shared__ float4 Ts4[128];
    __shared__ double red[64][15];

    char* KhiB = (char*)Khi_s;
    char* KloB = (char*)Klo_s;

    const int w    = blockIdx.x;
    const int xcd  = w & 7;
    const int idx  = w >> 3;
    const int b    = xcd * 4 + (idx >> 5);
    const int n0   = (idx & 31) * 64;
    const int blk  = b * 32 + (idx & 31);

    const int tid  = threadIdx.x;
    const int wv   = tid >> 6;
    const int lane = tid & 63;
    const int lr   = lane & 15;
    const int lg   = lane >> 4;
    const unsigned swl = (unsigned)((lr & 7) << 4);

    const float scale = 0.044194173824159216f;
    const float* kbase = tgt_embed + (size_t)b * N_ * D_;

    const int qrow = n0 + wv * 16 + lr;
    const float* qp = src_embed + ((size_t)b * N_ + qrow) * D_ + lg * 8;
    s16x8 qhi[16], qlo[16];
#pragma unroll
    for (int s = 0; s < 16; ++s) {
        const float4 f0 = *reinterpret_cast<const float4*>(qp + s * 32);
        const float4 f1 = *reinterpret_cast<const float4*>(qp + s * 32 + 4);
        const float x[8] = {f0.x, f0.y, f0.z, f0.w, f1.x, f1.y, f1.z, f1.w};
#pragma unroll
        for (int i = 0; i < 8; ++i) {
            const float v = x[i] * scale;
            const unsigned h = f2bf(v);
            qhi[s][i] = (short)h;
            qlo[s][i] = (short)f2bf(v - bf2f(h));
        }
    }

    float m_run = -1e30f, l_run = 0.f, a0 = 0.f, a1 = 0.f, a2 = 0.f;
    const int srow = tid >> 1;
    const int shalf = tid & 1;
    const unsigned swr = (unsigned)((srow & 7) << 4);

    for (int m0 = 0; m0 < N_; m0 += 128) {
        f32x4 acc[8];
#pragma unroll
        for (int nf = 0; nf < 8; ++nf) acc[nf] = (f32x4){0.f, 0.f, 0.f, 0.f};

#pragma unroll
        for (int kt = 0; kt < 8; ++kt) {
            __syncthreads();
            {
                const float* gp = kbase + (size_t)(m0 + srow) * D_ + kt * 64 + shalf * 32;
#pragma unroll
                for (int grp = 0; grp < 4; ++grp) {
                    const float4 fa = *reinterpret_cast<const float4*>(gp + grp * 8);
                    const float4 fb = *reinterpret_cast<const float4*>(gp + grp * 8 + 4);
                    const float x[8] = {fa.x, fa.y, fa.z, fa.w, fb.x, fb.y, fb.z, fb.w};
                    s16x8 hi, lo;
#pragma unroll
                    for (int i = 0; i < 8; ++i) {
                        const unsigned h = f2bf(x[i]);
                        hi[i] = (short)h;
                        lo[i] = (short)f2bf(x[i] - bf2f(h));
                    }
                    const unsigned off = (unsigned)srow * 128u +
                        (((unsigned)(shalf * 64 + grp * 16)) ^ swr);
                    *reinterpret_cast<s16x8*>(KhiB + off) = hi;
                    *reinterpret_cast<s16x8*>(KloB + off) = lo;
                }
                if (kt == 0 && tid < 128) {
                    const float* tp = tgt + ((size_t)b * N_ + m0 + tid) * 3;
                    Ts4[tid] = make_float4(tp[0], tp[1], tp[2], 0.f);
                }
            }
            __syncthreads();
#pragma unroll
            for (int ks = 0; ks < 2; ++ks) {
                const int s = kt * 2 + ks;
                const unsigned kb = ((unsigned)(lg * 16 + ks * 64)) ^ swl;
#pragma unroll
                for (int nf = 0; nf < 8; ++nf) {
                    const unsigned off = (unsigned)(nf * 16 + lr) * 128u + kb;
                    const s16x8 ah = *reinterpret_cast<const s16x8*>(KhiB + off);
                    const s16x8 al = *reinterpret_cast<const s16x8*>(KloB + off);
                    acc[nf] = __builtin_amdgcn_mfma_f32_16x16x32_bf16(ah, qhi[s], acc[nf], 0, 0, 0);
                    acc[nf] = __builtin_amdgcn_mfma_f32_16x16x32_bf16(al, qhi[s], acc[nf], 0, 0, 0);
                    acc[nf] = __builtin_amdgcn_mfma_f32_16x16x32_bf16(ah, qlo[s], acc[nf], 0, 0, 0);
                }
            }
        }

        float mx = -1e30f;
#pragma unroll
        for (int nf = 0; nf < 8; ++nf)
#pragma unroll
            for (int r = 0; r < 4; ++r) mx = fmaxf(mx, acc[nf][r]);
        mx = fmaxf(mx, __shfl_xor(mx, 16));
        mx = fmaxf(mx, __shfl_xor(mx, 32));

        const float mnew = fmaxf(m_run, mx);
        const float corr = __expf(m_run - mnew);
        l_run *= corr; a0 *= corr; a1 *= corr; a2 *= corr;

        float ps = 0.f, p0 = 0.f, p1 = 0.f, p2 = 0.f;
#pragma unroll
        for (int nf = 0; nf < 8; ++nf)
#pragma unroll
            for (int r = 0; r < 4; ++r) {
                const float p = __expf(acc[nf][r] - mnew);
                const int n = nf * 16 + lg * 4 + r;
                const float4 tv = Ts4[n];
                ps += p;
                p0 = fmaf(p, tv.x, p0);
                p1 = fmaf(p, tv.y, p1);
                p2 = fmaf(p, tv.z, p2);
            }
        l_run += ps; a0 += p0; a1 += p1; a2 += p2;
        m_run = mnew;
    }

    l_run += __shfl_xor(l_run, 16); l_run += __shfl_xor(l_run, 32);
    a0 += __shfl_xor(a0, 16); a0 += __shfl_xor(a0, 32);
    a1 += __shfl_xor(a1, 16); a1 += __shfl_xor(a1, 32);
    a2 += __shfl_xor(a2, 16); a2 += __shfl_xor(a2, 32);

    __syncthreads();
    if (lg == 0) {
        const float inv = 1.0f / l_run;
        const double mx0 = (double)(a0 * inv);
        const double mx1 = (double)(a1 * inv);
        const double mx2 = (double)(a2 * inv);
        const float* sp = src + ((size_t)b * N_ + qrow) * 3;
        const double s0 = sp[0], s1 = sp[1], s2 = sp[2];
        double* rp = red[wv * 16 + lr];
        rp[0] = s0;  rp[1] = s1;  rp[2] = s2;
        rp[3] = mx0; rp[4] = mx1; rp[5] = mx2;
        rp[6]  = s0 * mx0; rp[7]  = s0 * mx1; rp[8]  = s0 * mx2;
        rp[9]  = s1 * mx0; rp[10] = s1 * mx1; rp[11] = s1 * mx2;
        rp[12] = s2 * mx0; rp[13] = s2 * mx1; rp[14] = s2 * mx2;
    }
    __syncthreads();
    if (tid < 15) {
        double sum = 0.0;
        for (int j = 0; j < 64; ++j) sum += red[j][tid];
        partials[(size_t)blk * 15 + tid] = sum;
    }
}

// ---------------------------------------------------------------------------
// Kabsch (fp64), nbb = partial blocks per batch.
// ---------------------------------------------------------------------------
__global__ void kabsch_kernel(const double* __restrict__ partials,
                              float* __restrict__ out, int nbb)
{
    const int b = threadIdx.x;
    if (b >= B_) return;

    double acc[15];
#pragma unroll
    for (int i = 0; i < 15; ++i) acc[i] = 0.0;
    for (int rb = 0; rb < nbb; ++rb) {
        const double* p = partials + ((size_t)b * nbb + rb) * 15;
#pragma unroll
        for (int i = 0; i < 15; ++i) acc[i] += p[i];
    }

    const double invN = 1.0 / (double)N_;
    const double S[3] = {acc[0], acc[1], acc[2]};
    const double M[3] = {acc[3], acc[4], acc[5]};
    double H[3][3];
    for (int c = 0; c < 3; ++c)
        for (int d = 0; d < 3; ++d)
            H[c][d] = acc[6 + c * 3 + d] - S[c] * M[d] * invN;

    double A[3][3];
    for (int i = 0; i < 3; ++i)
        for (int j = 0; j < 3; ++j)
            A[i][j] = H[0][i] * H[0][j] + H[1][i] * H[1][j] + H[2][i] * H[2][j];

    double V[3][3] = {{1, 0, 0}, {0, 1, 0}, {0, 0, 1}};
    const int PQ[3][2] = {{0, 1}, {0, 2}, {1, 2}};
    for (int sweep = 0; sweep < 20; ++sweep) {
        const double off = fabs(A[0][1]) + fabs(A[0][2]) + fabs(A[1][2]);
        if (off < 1e-24) break;
        for (int pi = 0; pi < 3; ++pi) {
            const int p = PQ[pi][0], q = PQ[pi][1], rr = 3 - p - q;
            const double apq = A[p][q];
            if (fabs(apq) < 1e-300) continue;
            const double theta = (A[q][q] - A[p][p]) / (2.0 * apq);
            const double tt = (theta >= 0.0 ? 1.0 : -1.0) /
                              (fabs(theta) + sqrt(1.0 + theta * theta));
            const double c = 1.0 / sqrt(1.0 + tt * tt);
            const double sn = tt * c;
            const double app = A[p][p], aqq = A[q][q];
            const double arp = A[rr][p], arq = A[rr][q];
            A[p][p] = app - tt * apq;
            A[q][q] = aqq + tt * apq;
            A[p][q] = A[q][p] = 0.0;
            A[rr][p] = A[p][rr] = c * arp - sn * arq;
            A[rr][q] = A[q][rr] = sn * arp + c * arq;
            for (int k = 0; k < 3; ++k) {
                const double vkp = V[k][p], vkq = V[k][q];
                V[k][p] = c * vkp - sn * vkq;
                V[k][q] = sn * vkp + c * vkq;
            }
        }
    }

    double R[3][3] = {{0, 0, 0}, {0, 0, 0}, {0, 0, 0}};
    for (int i = 0; i < 3; ++i) {
        const double lam = A[i][i];
        const double sig = sqrt(lam > 0.0 ? lam : 0.0);
        const double inv = 1.0 / (sig > 1e-30 ? sig : 1e-30);
        double wv[3];
        for (int c = 0; c < 3; ++c)
            wv[c] = H[c][0] * V[0][i] + H[c][1] * V[1][i] + H[c][2] * V[2][i];
        for (int r = 0; r < 3; ++r)
            for (int c = 0; c < 3; ++c)
                R[r][c] += V[r][i] * wv[c] * inv;
    }

    const double det =
        R[0][0] * (R[1][1] * R[2][2] - R[1][2] * R[2][1]) -
        R[0][1] * (R[1][0] * R[2][2] - R[1][2] * R[2][0]) +
        R[0][2] * (R[1][0] * R[2][1] - R[1][1] * R[2][0]);
    if (det < 0.0) {
        R[2][0] = -R[2][0]; R[2][1] = -R[2][1]; R[2][2] = -R[2][2];
    }

    double t[3];
    for (int c = 0; c < 3; ++c)
        t[c] = M[c] * invN -
               (R[c][0] * S[0] + R[c][1] * S[1] + R[c][2] * S[2]) * invN;

    for (int r = 0; r < 3; ++r)
        for (int c = 0; c < 3; ++c)
            out[(size_t)b * 9 + r * 3 + c] = (float)R[r][c];
    for (int c = 0; c < 3; ++c)
        out[(size_t)B_ * 9 + (size_t)b * 3 + c] = (float)t[c];
}

// ---------------------------------------------------------------------------
extern "C" void kernel_launch(void* const* d_in, const int* in_sizes, int n_in,
                              void* d_out, int out_size, void* d_ws, size_t ws_size,
                              hipStream_t stream) {
    const float* src = (const float*)d_in[0];
    const float* tgt = (const float*)d_in[1];
    const float* se  = (const float*)d_in[2];
    const float* te  = (const float*)d_in[3];
    float* out = (float*)d_out;

    const size_t KP_OFF = 32768;
    const size_t need = KP_OFF + (size_t)B_ * N_ * D_ * 2;  // 67,141,632 B

    if (ws_size >= need) {
        u32x4* kp = (u32x4*)((char*)d_ws + KP_OFF);
        prepass_kernel<<<dim3(16384), dim3(256), 0, stream>>>(te, kp);
        attn_fast_kernel<<<dim3(256), dim3(512), 0, stream>>>(
            src, tgt, se, kp, (double*)d_ws);
        kabsch_kernel<<<dim3(1), dim3(64), 0, stream>>>((double*)d_ws, out, 8);
    } else {
        attn_v2_kernel<<<dim3(1024), dim3(256), 0, stream>>>(
            src, tgt, se, te, (double*)d_ws);
        kabsch_kernel<<<dim3(1), dim3(64), 0, stream>>>((double*)d_ws, out, 32);
    }
}

// Round 4
// 227.076 us; speedup vs baseline: 10.0726x; 1.1765x over previous
//
#include <hip/hip_runtime.h>
#include <hip/hip_fp16.h>
#include <math.h>

#define B_ 32
#define N_ 2048
#define D_ 512
#define NT 256     // 4 waves per block

typedef __attribute__((ext_vector_type(8))) _Float16 f16x8;
typedef __attribute__((ext_vector_type(8))) short s16x8;
typedef __attribute__((ext_vector_type(4))) float f32x4;
typedef __attribute__((ext_vector_type(4))) unsigned int u32x4;

__device__ inline unsigned packh2(float lo, float hi) {
    __half l = __float2half_rn(lo), h = __float2half_rn(hi);
    return (unsigned)__half_as_ushort(l) | ((unsigned)__half_as_ushort(h) << 16);
}
__device__ inline unsigned f2bf(float x) {
    unsigned u = __float_as_uint(x);
    return (u + 0x7FFFu + ((u >> 16) & 1u)) >> 16;
}
__device__ inline float bf2f(unsigned h) { return __uint_as_float(h << 16); }

// ---------------------------------------------------------------------------
// Pre-pass: tgt_embed fp32 -> fp16 plane, [b][mt 16][kt 16] tiles of 8KB.
// Tile byte (r*64 + s*16) holds K[row=r][k = kt*32 + (s ^ ((r>>1)&3))*8 .. +8].
// (identical layout to round 3 — measured 0 bank conflicts)
// ---------------------------------------------------------------------------
__global__ __launch_bounds__(256) void prepass_kernel(
    const float* __restrict__ te, u32x4* __restrict__ kp)
{
    const int idx = blockIdx.x * 256 + threadIdx.x;
    const int b   = idx >> 17;
    const int r17 = idx & 131071;
    const int mt  = r17 >> 13;
    const int kt  = (r17 >> 9) & 15;
    const int o16 = r17 & 511;
    const int r   = o16 >> 2;
    const int s   = o16 & 3;
    const int lg  = s ^ ((r >> 1) & 3);
    const float* src = te + (((size_t)b * N_ + mt * 128 + r) * D_ + kt * 32 + lg * 8);
    const float4 f0 = *(const float4*)src;
    const float4 f1 = *(const float4*)(src + 4);
    u32x4 u;
    u[0] = packh2(f0.x, f0.y);
    u[1] = packh2(f0.z, f0.w);
    u[2] = packh2(f1.x, f1.y);
    u[3] = packh2(f1.z, f1.w);
    kp[idx] = u;
}

// ---------------------------------------------------------------------------
// Attention kernel, pipelined: 512 blocks x 256 thr (4 waves). Block owns 128
// q-rows; wave owns 32 (2 B-frags, fp16 in regs). K tiles (128 rows x 32 k,
// 8KB) flow through a 4-slot LDS ring via global_load_lds, prefetch depth 3,
// counted s_waitcnt vmcnt(4) + raw s_barrier (never vmcnt(0) in-loop).
// All tgt coords for the batch live in LDS (loaded once). mfma(A=K, B=Q):
// lane owns q-row (col=lane&15) -> softmax is lane-local + 2 shuffles.
// ---------------------------------------------------------------------------
__global__ __launch_bounds__(NT, 2) void attn_pipe_kernel(
    const float* __restrict__ src, const float* __restrict__ tgt,
    const float* __restrict__ src_embed, const u32x4* __restrict__ kp,
    float* __restrict__ partials)
{
    __shared__ f16x8 ring[4][512];     // 32 KB: 4 x (128 rows x 32 k fp16)
    __shared__ float4 Ts4[N_];         // 32 KB: whole batch tgt coords
    __shared__ double red[4][15];

    const int tid  = threadIdx.x;
    const int wv   = tid >> 6;
    const int lane = tid & 63;
    const int lr   = lane & 15;
    const int lg   = lane >> 4;
    const int sxb  = (lg ^ ((lr >> 1) & 3)) << 4;   // swizzled 16B slot
    char* ringB = (char*)&ring[0][0];

    const int xcd  = blockIdx.x & 7;
    const int idx  = blockIdx.x >> 3;          // 0..63
    const int b    = xcd * 4 + (idx >> 4);     // 4 batches per XCD
    const int msl  = idx & 15;
    const int n0   = msl * 128;
    const int pblk = b * 16 + msl;

    // ---- prologue: Q -> fp16 regs (scale*log2e folded) ---------------------
    const float QSC = 0.044194173824159216f * 1.4426950408889634f;
    f16x8 Qr[2][16];
#pragma unroll
    for (int qf = 0; qf < 2; ++qf) {
        const int qrow = n0 + wv * 32 + qf * 16 + lr;
        const float* qp = src_embed + ((size_t)b * N_ + qrow) * D_ + lg * 8;
#pragma unroll
        for (int s = 0; s < 16; ++s) {
            const float4 f0 = *(const float4*)(qp + s * 32);
            const float4 f1 = *(const float4*)(qp + s * 32 + 4);
            u32x4 u;
            u[0] = packh2(f0.x * QSC, f0.y * QSC);
            u[1] = packh2(f0.z * QSC, f0.w * QSC);
            u[2] = packh2(f1.x * QSC, f1.y * QSC);
            u[3] = packh2(f1.z * QSC, f1.w * QSC);
            Qr[qf][s] = __builtin_bit_cast(f16x8, u);
        }
    }
    // ---- prologue: all tgt coords for this batch into LDS ------------------
    {
        const float* tb = tgt + (size_t)b * N_ * 3;
#pragma unroll
        for (int i = 0; i < 8; ++i) {
            const int r = tid + i * 256;
            Ts4[r] = make_float4(tb[r * 3], tb[r * 3 + 1], tb[r * 3 + 2], 0.f);
        }
    }
    __syncthreads();   // full drain: prologue vmem retired, Ts visible

#define STAGE(mc_, kt_, slot_) do {                                            \
    const u32x4* _g = kp + ((((size_t)b * 16 + (mc_)) * 16 + (kt_)) << 9);     \
    __builtin_amdgcn_global_load_lds(                                          \
        (const __attribute__((address_space(1))) void*)(_g + tid),             \
        (__attribute__((address_space(3))) void*)(&ring[slot_][wv * 64]),      \
        16, 0, 0);                                                             \
    __builtin_amdgcn_global_load_lds(                                          \
        (const __attribute__((address_space(1))) void*)(_g + 256 + tid),       \
        (__attribute__((address_space(3))) void*)(&ring[slot_][256 + wv * 64]),\
        16, 0, 0);                                                             \
} while (0)

    // prologue prefetch: tiles 0,1,2 (6 vmem instrs in flight per wave)
    STAGE(0, 0, 0);
    STAGE(0, 1, 1);
    STAGE(0, 2, 2);

    float m_s[2] = {-1e30f, -1e30f}, l_s[2] = {0.f, 0.f};
    float axs[2] = {0.f, 0.f}, ays[2] = {0.f, 0.f}, azs[2] = {0.f, 0.f};

    for (int mc = 0; mc < 16; ++mc) {
        f32x4 acc0[8], acc1[8];
#pragma unroll
        for (int nf = 0; nf < 8; ++nf) {
            acc0[nf] = (f32x4){0.f, 0.f, 0.f, 0.f};
            acc1[nf] = (f32x4){0.f, 0.f, 0.f, 0.f};
        }

#pragma unroll
        for (int kt = 0; kt < 16; ++kt) {
            const int t = (mc << 4) + kt;
            // tile t ready: 2 instrs/tile, tiles t+1,t+2 may stay in flight
            if (mc == 15 && kt >= 14) {
                asm volatile("s_waitcnt vmcnt(0)" ::: "memory");
            } else {
                asm volatile("s_waitcnt vmcnt(4)" ::: "memory");
            }
            __builtin_amdgcn_s_barrier();
            // stage tile t+3 into slot (t+3)&3 (== slot of tile t-1, whose
            // readers all completed before crossing barrier(t))
            if (t <= 252) {
                const int tn = t + 3;
                STAGE(tn >> 4, tn & 15, tn & 3);
            }
            const char* abase = ringB + ((t & 3) << 13) + lr * 64 + sxb;
#pragma unroll
            for (int nf = 0; nf < 8; ++nf) {
                const f16x8 a = *(const f16x8*)(abase + nf * 1024);
                acc0[nf] = __builtin_amdgcn_mfma_f32_16x16x32_f16(a, Qr[0][kt], acc0[nf], 0, 0, 0);
                acc1[nf] = __builtin_amdgcn_mfma_f32_16x16x32_f16(a, Qr[1][kt], acc1[nf], 0, 0, 0);
            }
        }

        // ---- online-softmax epilogue for this 128-row KV chunk -------------
        const float4* Ts = &Ts4[mc * 128];
        float mx0 = -1e30f, mx1 = -1e30f;
#pragma unroll
        for (int nf = 0; nf < 8; ++nf)
#pragma unroll
            for (int r4 = 0; r4 < 4; ++r4) {
                mx0 = fmaxf(mx0, acc0[nf][r4]);
                mx1 = fmaxf(mx1, acc1[nf][r4]);
            }
        mx0 = fmaxf(mx0, __shfl_xor(mx0, 16)); mx0 = fmaxf(mx0, __shfl_xor(mx0, 32));
        mx1 = fmaxf(mx1, __shfl_xor(mx1, 16)); mx1 = fmaxf(mx1, __shfl_xor(mx1, 32));
        const float mn0 = fmaxf(m_s[0], mx0), mn1 = fmaxf(m_s[1], mx1);
        const float c0 = exp2f(m_s[0] - mn0), c1 = exp2f(m_s[1] - mn1);
        l_s[0] *= c0; axs[0] *= c0; ays[0] *= c0; azs[0] *= c0; m_s[0] = mn0;
        l_s[1] *= c1; axs[1] *= c1; ays[1] *= c1; azs[1] *= c1; m_s[1] = mn1;
        float l0 = 0.f, x0 = 0.f, y0 = 0.f, z0 = 0.f;
        float l1 = 0.f, x1 = 0.f, y1 = 0.f, z1 = 0.f;
#pragma unroll
        for (int nf = 0; nf < 8; ++nf)
#pragma unroll
            for (int r4 = 0; r4 < 4; ++r4) {
                const float4 tv = Ts[nf * 16 + lg * 4 + r4];
                const float p0 = exp2f(acc0[nf][r4] - mn0);
                const float p1 = exp2f(acc1[nf][r4] - mn1);
                l0 += p0; x0 = fmaf(p0, tv.x, x0); y0 = fmaf(p0, tv.y, y0); z0 = fmaf(p0, tv.z, z0);
                l1 += p1; x1 = fmaf(p1, tv.x, x1); y1 = fmaf(p1, tv.y, y1); z1 = fmaf(p1, tv.z, z1);
            }
        l_s[0] += l0; axs[0] += x0; ays[0] += y0; azs[0] += z0;
        l_s[1] += l1; axs[1] += x1; ays[1] += y1; azs[1] += z1;
    }
#undef STAGE

    // ---- finalize: reduce lane-replicas, form per-block 15 partials --------
    double dl[15];
#pragma unroll
    for (int i = 0; i < 15; ++i) dl[i] = 0.0;
#pragma unroll
    for (int qf = 0; qf < 2; ++qf) {
        float lt = l_s[qf], x = axs[qf], y = ays[qf], z = azs[qf];
        lt += __shfl_xor(lt, 16); lt += __shfl_xor(lt, 32);
        x  += __shfl_xor(x, 16);  x  += __shfl_xor(x, 32);
        y  += __shfl_xor(y, 16);  y  += __shfl_xor(y, 32);
        z  += __shfl_xor(z, 16);  z  += __shfl_xor(z, 32);
        if (lg == 0) {
            const int qrow = n0 + wv * 32 + qf * 16 + lr;
            const float* sp = src + ((size_t)b * N_ + qrow) * 3;
            const double inv = 1.0 / (double)lt;
            const double m0d = (double)x * inv, m1d = (double)y * inv, m2d = (double)z * inv;
            const double s0 = sp[0], s1 = sp[1], s2 = sp[2];
            dl[0] += s0;  dl[1] += s1;  dl[2] += s2;
            dl[3] += m0d; dl[4] += m1d; dl[5] += m2d;
            dl[6]  += s0 * m0d; dl[7]  += s0 * m1d; dl[8]  += s0 * m2d;
            dl[9]  += s1 * m0d; dl[10] += s1 * m1d; dl[11] += s1 * m2d;
            dl[12] += s2 * m0d; dl[13] += s2 * m1d; dl[14] += s2 * m2d;
        }
    }
#pragma unroll
    for (int i = 0; i < 15; ++i) {
        double v = dl[i];
        for (int off = 1; off < 64; off <<= 1) v += __shfl_xor(v, off);
        dl[i] = v;
    }
    if (lane == 0) {
#pragma unroll
        for (int i = 0; i < 15; ++i) red[wv][i] = dl[i];
    }
    __syncthreads();
    if (tid < 15) {
        double sum = 0.0;
        for (int w = 0; w < 4; ++w) sum += red[w][tid];
        partials[(size_t)pblk * 15 + tid] = (float)sum;
    }
}

// ---------------------------------------------------------------------------
// Fallback (proven round-2 kernel): bf16 hi/lo 3-product, 1024 blocks.
// ---------------------------------------------------------------------------
__global__ __launch_bounds__(256, 2) void attn_v2_kernel(
    const float* __restrict__ src, const float* __restrict__ tgt,
    const float* __restrict__ src_embed, const float* __restrict__ tgt_embed,
    float* __restrict__ partials)
{
    __shared__ short Khi_s[128 * 64];
    __shared__ short Klo_s[128 * 64];
    __shared__ float4 Ts4[128];
    __shared__ double red[64][15];

    char* KhiB = (char*)Khi_s;
    char* KloB = (char*)Klo_s;

    const int w    = blockIdx.x;
    const int xcd  = w & 7;
    const int idx  = w >> 3;
    const int b    = xcd * 4 + (idx >> 5);
    const int n0   = (idx & 31) * 64;
    const int blk  = b * 32 + (idx & 31);

    const int tid  = threadIdx.x;
    const int wv   = tid >> 6;
    const int lane = tid & 63;
    const int lr   = lane & 15;
    const int lg   = lane >> 4;
    const unsigned swl = (unsigned)((lr & 7) << 4);

    const float scale = 0.044194173824159216f;
    const float* kbase = tgt_embed + (size_t)b * N_ * D_;

    const int qrow = n0 + wv * 16 + lr;
    const float* qp = src_embed + ((size_t)b * N_ + qrow) * D_ + lg * 8;
    s16x8 qhi[16], qlo[16];
#pragma unroll
    for (int s = 0; s < 16; ++s) {
        const float4 f0 = *reinterpret_cast<const float4*>(qp + s * 32);
        const float4 f1 = *reinterpret_cast<const float4*>(qp + s * 32 + 4);
        const float x[8] = {f0.x, f0.y, f0.z, f0.w, f1.x, f1.y, f1.z, f1.w};
#pragma unroll
        for (int i = 0; i < 8; ++i) {
            const float v = x[i] * scale;
            const unsigned h = f2bf(v);
            qhi[s][i] = (short)h;
            qlo[s][i] = (short)f2bf(v - bf2f(h));
        }
    }

    float m_run = -1e30f, l_run = 0.f, a0 = 0.f, a1 = 0.f, a2 = 0.f;
    const int srow = tid >> 1;
    const int shalf = tid & 1;
    const unsigned swr = (unsigned)((srow & 7) << 4);

    for (int m0 = 0; m0 < N_; m0 += 128) {
        f32x4 acc[8];
#pragma unroll
        for (int nf = 0; nf < 8; ++nf) acc[nf] = (f32x4){0.f, 0.f, 0.f, 0.f};

#pragma unroll
        for (int kt = 0; kt < 8; ++kt) {
            __syncthreads();
            {
                const float* gp = kbase + (size_t)(m0 + srow) * D_ + kt * 64 + shalf * 32;
#pragma unroll
                for (int grp = 0; grp < 4; ++grp) {
                    const float4 fa = *reinterpret_cast<const float4*>(gp + grp * 8);
                    const float4 fb = *reinterpret_cast<const float4*>(gp + grp * 8 + 4);
                    const float x[8] = {fa.x, fa.y, fa.z, fa.w, fb.x, fb.y, fb.z, fb.w};
                    s16x8 hi, lo;
#pragma unroll
                    for (int i = 0; i < 8; ++i) {
                        const unsigned h = f2bf(x[i]);
                        hi[i] = (short)h;
                        lo[i] = (short)f2bf(x[i] - bf2f(h));
                    }
                    const unsigned off = (unsigned)srow * 128u +
                        (((unsigned)(shalf * 64 + grp * 16)) ^ swr);
                    *reinterpret_cast<s16x8*>(KhiB + off) = hi;
                    *reinterpret_cast<s16x8*>(KloB + off) = lo;
                }
                if (kt == 0 && tid < 128) {
                    const float* tp = tgt + ((size_t)b * N_ + m0 + tid) * 3;
                    Ts4[tid] = make_float4(tp[0], tp[1], tp[2], 0.f);
                }
            }
            __syncthreads();
#pragma unroll
            for (int ks = 0; ks < 2; ++ks) {
                const int s = kt * 2 + ks;
                const unsigned kb = ((unsigned)(lg * 16 + ks * 64)) ^ swl;
#pragma unroll
                for (int nf = 0; nf < 8; ++nf) {
                    const unsigned off = (unsigned)(nf * 16 + lr) * 128u + kb;
                    const s16x8 ah = *reinterpret_cast<const s16x8*>(KhiB + off);
                    const s16x8 al = *reinterpret_cast<const s16x8*>(KloB + off);
                    acc[nf] = __builtin_amdgcn_mfma_f32_16x16x32_bf16(ah, qhi[s], acc[nf], 0, 0, 0);
                    acc[nf] = __builtin_amdgcn_mfma_f32_16x16x32_bf16(al, qhi[s], acc[nf], 0, 0, 0);
                    acc[nf] = __builtin_amdgcn_mfma_f32_16x16x32_bf16(ah, qlo[s], acc[nf], 0, 0, 0);
                }
            }
        }

        float mx = -1e30f;
#pragma unroll
        for (int nf = 0; nf < 8; ++nf)
#pragma unroll
            for (int r = 0; r < 4; ++r) mx = fmaxf(mx, acc[nf][r]);
        mx = fmaxf(mx, __shfl_xor(mx, 16));
        mx = fmaxf(mx, __shfl_xor(mx, 32));

        const float mnew = fmaxf(m_run, mx);
        const float corr = __expf(m_run - mnew);
        l_run *= corr; a0 *= corr; a1 *= corr; a2 *= corr;

        float ps = 0.f, p0 = 0.f, p1 = 0.f, p2 = 0.f;
#pragma unroll
        for (int nf = 0; nf < 8; ++nf)
#pragma unroll
            for (int r = 0; r < 4; ++r) {
                const float p = __expf(acc[nf][r] - mnew);
                const int n = nf * 16 + lg * 4 + r;
                const float4 tv = Ts4[n];
                ps += p;
                p0 = fmaf(p, tv.x, p0);
                p1 = fmaf(p, tv.y, p1);
                p2 = fmaf(p, tv.z, p2);
            }
        l_run += ps; a0 += p0; a1 += p1; a2 += p2;
        m_run = mnew;
    }

    l_run += __shfl_xor(l_run, 16); l_run += __shfl_xor(l_run, 32);
    a0 += __shfl_xor(a0, 16); a0 += __shfl_xor(a0, 32);
    a1 += __shfl_xor(a1, 16); a1 += __shfl_xor(a1, 32);
    a2 += __shfl_xor(a2, 16); a2 += __shfl_xor(a2, 32);

    __syncthreads();
    if (lg == 0) {
        const float inv = 1.0f / l_run;
        const double mx0 = (double)(a0 * inv);
        const double mx1 = (double)(a1 * inv);
        const double mx2 = (double)(a2 * inv);
        const float* sp = src + ((size_t)b * N_ + qrow) * 3;
        const double s0 = sp[0], s1 = sp[1], s2 = sp[2];
        double* rp = red[wv * 16 + lr];
        rp[0] = s0;  rp[1] = s1;  rp[2] = s2;
        rp[3] = mx0; rp[4] = mx1; rp[5] = mx2;
        rp[6]  = s0 * mx0; rp[7]  = s0 * mx1; rp[8]  = s0 * mx2;
        rp[9]  = s1 * mx0; rp[10] = s1 * mx1; rp[11] = s1 * mx2;
        rp[12] = s2 * mx0; rp[13] = s2 * mx1; rp[14] = s2 * mx2;
    }
    __syncthreads();
    if (tid < 15) {
        double sum = 0.0;
        for (int j = 0; j < 64; ++j) sum += red[j][tid];
        partials[(size_t)blk * 15 + tid] = (float)sum;
    }
}

// ---------------------------------------------------------------------------
// Kabsch (fp64 internals, float partials), nbb = partial blocks per batch.
// ---------------------------------------------------------------------------
__global__ void kabsch_kernel(const float* __restrict__ partials,
                              float* __restrict__ out, int nbb)
{
    const int b = threadIdx.x;
    if (b >= B_) return;

    double acc[15];
#pragma unroll
    for (int i = 0; i < 15; ++i) acc[i] = 0.0;
    for (int rb = 0; rb < nbb; ++rb) {
        const float* p = partials + ((size_t)b * nbb + rb) * 15;
#pragma unroll
        for (int i = 0; i < 15; ++i) acc[i] += (double)p[i];
    }

    const double invN = 1.0 / (double)N_;
    const double S[3] = {acc[0], acc[1], acc[2]};
    const double M[3] = {acc[3], acc[4], acc[5]};
    double H[3][3];
    for (int c = 0; c < 3; ++c)
        for (int d = 0; d < 3; ++d)
            H[c][d] = acc[6 + c * 3 + d] - S[c] * M[d] * invN;

    double A[3][3];
    for (int i = 0; i < 3; ++i)
        for (int j = 0; j < 3; ++j)
            A[i][j] = H[0][i] * H[0][j] + H[1][i] * H[1][j] + H[2][i] * H[2][j];

    double V[3][3] = {{1, 0, 0}, {0, 1, 0}, {0, 0, 1}};
    const int PQ[3][2] = {{0, 1}, {0, 2}, {1, 2}};
    for (int sweep = 0; sweep < 20; ++sweep) {
        const double off = fabs(A[0][1]) + fabs(A[0][2]) + fabs(A[1][2]);
        if (off < 1e-24) break;
        for (int pi = 0; pi < 3; ++pi) {
            const int p = PQ[pi][0], q = PQ[pi][1], rr = 3 - p - q;
            const double apq = A[p][q];
            if (fabs(apq) < 1e-300) continue;
            const double theta = (A[q][q] - A[p][p]) / (2.0 * apq);
            const double tt = (theta >= 0.0 ? 1.0 : -1.0) /
                              (fabs(theta) + sqrt(1.0 + theta * theta));
            const double c = 1.0 / sqrt(1.0 + tt * tt);
            const double sn = tt * c;
            const double app = A[p][p], aqq = A[q][q];
            const double arp = A[rr][p], arq = A[rr][q];
            A[p][p] = app - tt * apq;
            A[q][q] = aqq + tt * apq;
            A[p][q] = A[q][p] = 0.0;
            A[rr][p] = A[p][rr] = c * arp - sn * arq;
            A[rr][q] = A[q][rr] = sn * arp + c * arq;
            for (int k = 0; k < 3; ++k) {
                const double vkp = V[k][p], vkq = V[k][q];
                V[k][p] = c * vkp - sn * vkq;
                V[k][q] = sn * vkp + c * vkq;
            }
        }
    }

    double R[3][3] = {{0, 0, 0}, {0, 0, 0}, {0, 0, 0}};
    for (int i = 0; i < 3; ++i) {
        const double lam = A[i][i];
        const double sig = sqrt(lam > 0.0 ? lam : 0.0);
        const double inv = 1.0 / (sig > 1e-30 ? sig : 1e-30);
        double wv[3];
        for (int c = 0; c < 3; ++c)
            wv[c] = H[c][0] * V[0][i] + H[c][1] * V[1][i] + H[c][2] * V[2][i];
        for (int r = 0; r < 3; ++r)
            for (int c = 0; c < 3; ++c)
                R[r][c] += V[r][i] * wv[c] * inv;
    }

    const double det =
        R[0][0] * (R[1][1] * R[2][2] - R[1][2] * R[2][1]) -
        R[0][1] * (R[1][0] * R[2][2] - R[1][2] * R[2][0]) +
        R[0][2] * (R[1][0] * R[2][1] - R[1][1] * R[2][0]);
    if (det < 0.0) {
        R[2][0] = -R[2][0]; R[2][1] = -R[2][1]; R[2][2] = -R[2][2];
    }

    double t[3];
    for (int c = 0; c < 3; ++c)
        t[c] = M[c] * invN -
               (R[c][0] * S[0] + R[c][1] * S[1] + R[c][2] * S[2]) * invN;

    for (int r = 0; r < 3; ++r)
        for (int c = 0; c < 3; ++c)
            out[(size_t)b * 9 + r * 3 + c] = (float)R[r][c];
    for (int c = 0; c < 3; ++c)
        out[(size_t)B_ * 9 + (size_t)b * 3 + c] = (float)t[c];
}

// ---------------------------------------------------------------------------
extern "C" void kernel_launch(void* const* d_in, const int* in_sizes, int n_in,
                              void* d_out, int out_size, void* d_ws, size_t ws_size,
                              hipStream_t stream) {
    const float* src = (const float*)d_in[0];
    const float* tgt = (const float*)d_in[1];
    const float* se  = (const float*)d_in[2];
    const float* te  = (const float*)d_in[3];
    float* out = (float*)d_out;

    const size_t KP_OFF = 32768;   // float partials: 512*15*4 = 30720 B
    const size_t need = KP_OFF + (size_t)B_ * N_ * D_ * 2;  // 67,141,632 B

    if (ws_size >= need) {
        u32x4* kp = (u32x4*)((char*)d_ws + KP_OFF);
        prepass_kernel<<<dim3(16384), dim3(256), 0, stream>>>(te, kp);
        attn_pipe_kernel<<<dim3(512), dim3(NT), 0, stream>>>(
            src, tgt, se, kp, (float*)d_ws);
        kabsch_kernel<<<dim3(1), dim3(64), 0, stream>>>((float*)d_ws, out, 16);
    } else {
        attn_v2_kernel<<<dim3(1024), dim3(256), 0, stream>>>(
            src, tgt, se, te, (float*)d_ws);
        kabsch_kernel<<<dim3(1), dim3(64), 0, stream>>>((float*)d_ws, out, 32);
    }
}

// Round 5
// 225.677 us; speedup vs baseline: 10.1351x; 1.0062x over previous
//
#include <hip/hip_runtime.h>
#include <hip/hip_fp16.h>
#include <math.h>

#define B_ 32
#define N_ 2048
#define D_ 512
#define NT 256     // 4 waves per block

typedef __attribute__((ext_vector_type(8))) _Float16 f16x8;
typedef __attribute__((ext_vector_type(8))) short s16x8;
typedef __attribute__((ext_vector_type(4))) float f32x4;
typedef __attribute__((ext_vector_type(4))) unsigned int u32x4;

__device__ inline unsigned packh2(float lo, float hi) {
    __half l = __float2half_rn(lo), h = __float2half_rn(hi);
    return (unsigned)__half_as_ushort(l) | ((unsigned)__half_as_ushort(h) << 16);
}
__device__ inline unsigned f2bf(float x) {
    unsigned u = __float_as_uint(x);
    return (u + 0x7FFFu + ((u >> 16) & 1u)) >> 16;
}
__device__ inline float bf2f(unsigned h) { return __uint_as_float(h << 16); }

// ---------------------------------------------------------------------------
// Pre-pass: tgt_embed fp32 -> fp16 plane, [b][mt 16][kt 16] tiles of 8KB.
// Tile byte (r*64 + s*16) holds K[row=r][k = kt*32 + (s ^ ((r>>1)&3))*8 .. +8].
// ---------------------------------------------------------------------------
__global__ __launch_bounds__(256) void prepass_kernel(
    const float* __restrict__ te, u32x4* __restrict__ kp)
{
    const int idx = blockIdx.x * 256 + threadIdx.x;
    const int b   = idx >> 17;
    const int r17 = idx & 131071;
    const int mt  = r17 >> 13;
    const int kt  = (r17 >> 9) & 15;
    const int o16 = r17 & 511;
    const int r   = o16 >> 2;
    const int s   = o16 & 3;
    const int lg  = s ^ ((r >> 1) & 3);
    const float* src = te + (((size_t)b * N_ + mt * 128 + r) * D_ + kt * 32 + lg * 8);
    const float4 f0 = *(const float4*)src;
    const float4 f1 = *(const float4*)(src + 4);
    u32x4 u;
    u[0] = packh2(f0.x, f0.y);
    u[1] = packh2(f0.z, f0.w);
    u[2] = packh2(f1.x, f1.y);
    u[3] = packh2(f1.z, f1.w);
    kp[idx] = u;
}

// ---------------------------------------------------------------------------
// Attention kernel, group-double-buffered: 512 blocks x 256 thr (4 waves).
// Block owns 128 q-rows; wave owns 32 (2 B-frags, fp16 in regs). K flows in
// 32KB groups (4 tiles of 128 rows x 32 k) through a 2-half LDS buffer:
// one __syncthreads per group (64 total), stage group g+1 right after the
// barrier (drained one full group later -> latency fully covered).
// mfma(A=K, B=Q): lane owns q-row (col=lane&15) -> softmax lane-local.
// ---------------------------------------------------------------------------
__global__ __launch_bounds__(NT, 2) void attn_db_kernel(
    const float* __restrict__ src, const float* __restrict__ tgt,
    const float* __restrict__ src_embed, const u32x4* __restrict__ kp,
    float* __restrict__ partials)
{
    __shared__ f16x8 Kbuf[2][4][512];   // 64 KB: 2 halves x 4 tiles x 8KB
    __shared__ float4 TsB[2][128];      // 4 KB: per-mc tgt coords, DB
    __shared__ double red[4][15];

    const int tid  = threadIdx.x;
    const int wv   = tid >> 6;
    const int lane = tid & 63;
    const int lr   = lane & 15;
    const int lg   = lane >> 4;
    const int sxb  = (lg ^ ((lr >> 1) & 3)) << 4;   // swizzled 16B slot
    char* KbufB = (char*)&Kbuf[0][0][0];

    const int xcd  = blockIdx.x & 7;
    const int idx  = blockIdx.x >> 3;          // 0..63
    const int b    = xcd * 4 + (idx >> 4);     // 4 batches per XCD
    const int msl  = idx & 15;
    const int n0   = msl * 128;
    const int pblk = b * 16 + msl;

    // ---- prologue: Q -> fp16 regs (scale*log2e folded) ---------------------
    const float QSC = 0.044194173824159216f * 1.4426950408889634f;
    f16x8 Qr[2][16];
#pragma unroll
    for (int qf = 0; qf < 2; ++qf) {
        const int qrow = n0 + wv * 32 + qf * 16 + lr;
        const float* qp = src_embed + ((size_t)b * N_ + qrow) * D_ + lg * 8;
#pragma unroll
        for (int s = 0; s < 16; ++s) {
            const float4 f0 = *(const float4*)(qp + s * 32);
            const float4 f1 = *(const float4*)(qp + s * 32 + 4);
            u32x4 u;
            u[0] = packh2(f0.x * QSC, f0.y * QSC);
            u[1] = packh2(f0.z * QSC, f0.w * QSC);
            u[2] = packh2(f1.x * QSC, f1.y * QSC);
            u[3] = packh2(f1.z * QSC, f1.w * QSC);
            Qr[qf][s] = __builtin_bit_cast(f16x8, u);
        }
    }
    // ---- prologue: Ts for mc=0 ---------------------------------------------
    if (tid < 128) {
        const float* tp = tgt + ((size_t)b * N_ + tid) * 3;
        TsB[0][tid] = make_float4(tp[0], tp[1], tp[2], 0.f);
    }

    // stage 2 tiles of group gi (ti, ti+1 handled by pairs below)
#define STAGE_TILE(t_, half_, ti_) do {                                        \
    const u32x4* _g = kp +                                                     \
        ((((size_t)b * 16 + ((t_) >> 4)) * 16 + ((t_) & 15)) << 9);            \
    __builtin_amdgcn_global_load_lds(                                          \
        (const __attribute__((address_space(1))) void*)(_g + tid),             \
        (__attribute__((address_space(3))) void*)(&Kbuf[half_][ti_][wv * 64]), \
        16, 0, 0);                                                             \
    __builtin_amdgcn_global_load_lds(                                          \
        (const __attribute__((address_space(1))) void*)(_g + 256 + tid),       \
        (__attribute__((address_space(3))) void*)(&Kbuf[half_][ti_][256 + wv * 64]),\
        16, 0, 0);                                                             \
} while (0)

#define STAGE_GROUP(gi_, half_) do {                                           \
    STAGE_TILE(4 * (gi_) + 0, half_, 0);                                       \
    STAGE_TILE(4 * (gi_) + 1, half_, 1);                                       \
    STAGE_TILE(4 * (gi_) + 2, half_, 2);                                       \
    STAGE_TILE(4 * (gi_) + 3, half_, 3);                                       \
} while (0)

    // prologue prefetch: group 0 -> half 0
    STAGE_GROUP(0, 0);

    float m_s[2] = {-1e30f, -1e30f}, l_s[2] = {0.f, 0.f};
    float axs[2] = {0.f, 0.f}, ays[2] = {0.f, 0.f}, azs[2] = {0.f, 0.f};

    f32x4 acc0[8], acc1[8];

    for (int g4 = 0; g4 < 16; ++g4) {      // g4 == mc
#pragma unroll
        for (int gm = 0; gm < 4; ++gm) {   // group g = 4*g4 + gm
            const int g = (g4 << 2) | gm;
            __syncthreads();               // half (g&1) ready; prev reads done
            if (g < 63) {
                const int gn = g + 1;
                STAGE_GROUP(gn, gn & 1);   // drained at NEXT group top
            }
            // Ts prefetch for mc+1 (last group of each mc)
            float tv0 = 0.f, tv1 = 0.f, tv2 = 0.f;
            const bool pf = (gm == 3) && (g4 < 15) && (tid < 128);
            if (pf) {
                const float* tp = tgt + ((size_t)b * N_ + (g4 + 1) * 128 + tid) * 3;
                tv0 = tp[0]; tv1 = tp[1]; tv2 = tp[2];
            }
            if (gm == 0) {
#pragma unroll
                for (int nf = 0; nf < 8; ++nf) {
                    acc0[nf] = (f32x4){0.f, 0.f, 0.f, 0.f};
                    acc1[nf] = (f32x4){0.f, 0.f, 0.f, 0.f};
                }
            }
            __builtin_amdgcn_s_setprio(1);
#pragma unroll
            for (int ti = 0; ti < 4; ++ti) {
                const int kt = (gm << 2) | ti;   // compile-time
                const char* abase = KbufB + ((g & 1) << 15) + (ti << 13)
                                  + lr * 64 + sxb;
#pragma unroll
                for (int nf = 0; nf < 8; ++nf) {
                    const f16x8 a = *(const f16x8*)(abase + nf * 1024);
                    acc0[nf] = __builtin_amdgcn_mfma_f32_16x16x32_f16(a, Qr[0][kt], acc0[nf], 0, 0, 0);
                    acc1[nf] = __builtin_amdgcn_mfma_f32_16x16x32_f16(a, Qr[1][kt], acc1[nf], 0, 0, 0);
                }
            }
            __builtin_amdgcn_s_setprio(0);
            if (pf)
                TsB[(g4 + 1) & 1][tid] = make_float4(tv0, tv1, tv2, 0.f);

            if (gm == 3) {
                // ---- online-softmax epilogue for this 128-row KV chunk -----
                const float4* Ts = &TsB[g4 & 1][0];
                float mx0 = -1e30f, mx1 = -1e30f;
#pragma unroll
                for (int nf = 0; nf < 8; ++nf)
#pragma unroll
                    for (int r4 = 0; r4 < 4; ++r4) {
                        mx0 = fmaxf(mx0, acc0[nf][r4]);
                        mx1 = fmaxf(mx1, acc1[nf][r4]);
                    }
                mx0 = fmaxf(mx0, __shfl_xor(mx0, 16)); mx0 = fmaxf(mx0, __shfl_xor(mx0, 32));
                mx1 = fmaxf(mx1, __shfl_xor(mx1, 16)); mx1 = fmaxf(mx1, __shfl_xor(mx1, 32));
                const float mn0 = fmaxf(m_s[0], mx0), mn1 = fmaxf(m_s[1], mx1);
                const float c0 = exp2f(m_s[0] - mn0), c1 = exp2f(m_s[1] - mn1);
                l_s[0] *= c0; axs[0] *= c0; ays[0] *= c0; azs[0] *= c0; m_s[0] = mn0;
                l_s[1] *= c1; axs[1] *= c1; ays[1] *= c1; azs[1] *= c1; m_s[1] = mn1;
                float l0 = 0.f, x0 = 0.f, y0 = 0.f, z0 = 0.f;
                float l1 = 0.f, x1 = 0.f, y1 = 0.f, z1 = 0.f;
#pragma unroll
                for (int nf = 0; nf < 8; ++nf)
#pragma unroll
                    for (int r4 = 0; r4 < 4; ++r4) {
                        const float4 tv = Ts[nf * 16 + lg * 4 + r4];
                        const float p0 = exp2f(acc0[nf][r4] - mn0);
                        const float p1 = exp2f(acc1[nf][r4] - mn1);
                        l0 += p0; x0 = fmaf(p0, tv.x, x0); y0 = fmaf(p0, tv.y, y0); z0 = fmaf(p0, tv.z, z0);
                        l1 += p1; x1 = fmaf(p1, tv.x, x1); y1 = fmaf(p1, tv.y, y1); z1 = fmaf(p1, tv.z, z1);
                    }
                l_s[0] += l0; axs[0] += x0; ays[0] += y0; azs[0] += z0;
                l_s[1] += l1; axs[1] += x1; ays[1] += y1; azs[1] += z1;
            }
        }
    }
#undef STAGE_GROUP
#undef STAGE_TILE

    // ---- finalize: reduce lane-replicas, form per-block 15 partials --------
    double dl[15];
#pragma unroll
    for (int i = 0; i < 15; ++i) dl[i] = 0.0;
#pragma unroll
    for (int qf = 0; qf < 2; ++qf) {
        float lt = l_s[qf], x = axs[qf], y = ays[qf], z = azs[qf];
        lt += __shfl_xor(lt, 16); lt += __shfl_xor(lt, 32);
        x  += __shfl_xor(x, 16);  x  += __shfl_xor(x, 32);
        y  += __shfl_xor(y, 16);  y  += __shfl_xor(y, 32);
        z  += __shfl_xor(z, 16);  z  += __shfl_xor(z, 32);
        if (lg == 0) {
            const int qrow = n0 + wv * 32 + qf * 16 + lr;
            const float* sp = src + ((size_t)b * N_ + qrow) * 3;
            const double inv = 1.0 / (double)lt;
            const double m0d = (double)x * inv, m1d = (double)y * inv, m2d = (double)z * inv;
            const double s0 = sp[0], s1 = sp[1], s2 = sp[2];
            dl[0] += s0;  dl[1] += s1;  dl[2] += s2;
            dl[3] += m0d; dl[4] += m1d; dl[5] += m2d;
            dl[6]  += s0 * m0d; dl[7]  += s0 * m1d; dl[8]  += s0 * m2d;
            dl[9]  += s1 * m0d; dl[10] += s1 * m1d; dl[11] += s1 * m2d;
            dl[12] += s2 * m0d; dl[13] += s2 * m1d; dl[14] += s2 * m2d;
        }
    }
#pragma unroll
    for (int i = 0; i < 15; ++i) {
        double v = dl[i];
        for (int off = 1; off < 64; off <<= 1) v += __shfl_xor(v, off);
        dl[i] = v;
    }
    if (lane == 0) {
#pragma unroll
        for (int i = 0; i < 15; ++i) red[wv][i] = dl[i];
    }
    __syncthreads();
    if (tid < 15) {
        double sum = 0.0;
        for (int w = 0; w < 4; ++w) sum += red[w][tid];
        partials[(size_t)pblk * 15 + tid] = (float)sum;
    }
}

// ---------------------------------------------------------------------------
// Fallback (proven round-2 kernel): bf16 hi/lo 3-product, 1024 blocks.
// ---------------------------------------------------------------------------
__global__ __launch_bounds__(256, 2) void attn_v2_kernel(
    const float* __restrict__ src, const float* __restrict__ tgt,
    const float* __restrict__ src_embed, const float* __restrict__ tgt_embed,
    float* __restrict__ partials)
{
    __shared__ short Khi_s[128 * 64];
    __shared__ short Klo_s[128 * 64];
    __shared__ float4 Ts4[128];
    __shared__ double red[64][15];

    char* KhiB = (char*)Khi_s;
    char* KloB = (char*)Klo_s;

    const int w    = blockIdx.x;
    const int xcd  = w & 7;
    const int idx  = w >> 3;
    const int b    = xcd * 4 + (idx >> 5);
    const int n0   = (idx & 31) * 64;
    const int blk  = b * 32 + (idx & 31);

    const int tid  = threadIdx.x;
    const int wv   = tid >> 6;
    const int lane = tid & 63;
    const int lr   = lane & 15;
    const int lg   = lane >> 4;
    const unsigned swl = (unsigned)((lr & 7) << 4);

    const float scale = 0.044194173824159216f;
    const float* kbase = tgt_embed + (size_t)b * N_ * D_;

    const int qrow = n0 + wv * 16 + lr;
    const float* qp = src_embed + ((size_t)b * N_ + qrow) * D_ + lg * 8;
    s16x8 qhi[16], qlo[16];
#pragma unroll
    for (int s = 0; s < 16; ++s) {
        const float4 f0 = *reinterpret_cast<const float4*>(qp + s * 32);
        const float4 f1 = *reinterpret_cast<const float4*>(qp + s * 32 + 4);
        const float x[8] = {f0.x, f0.y, f0.z, f0.w, f1.x, f1.y, f1.z, f1.w};
#pragma unroll
        for (int i = 0; i < 8; ++i) {
            const float v = x[i] * scale;
            const unsigned h = f2bf(v);
            qhi[s][i] = (short)h;
            qlo[s][i] = (short)f2bf(v - bf2f(h));
        }
    }

    float m_run = -1e30f, l_run = 0.f, a0 = 0.f, a1 = 0.f, a2 = 0.f;
    const int srow = tid >> 1;
    const int shalf = tid & 1;
    const unsigned swr = (unsigned)((srow & 7) << 4);

    for (int m0 = 0; m0 < N_; m0 += 128) {
        f32x4 acc[8];
#pragma unroll
        for (int nf = 0; nf < 8; ++nf) acc[nf] = (f32x4){0.f, 0.f, 0.f, 0.f};

#pragma unroll
        for (int kt = 0; kt < 8; ++kt) {
            __syncthreads();
            {
                const float* gp = kbase + (size_t)(m0 + srow) * D_ + kt * 64 + shalf * 32;
#pragma unroll
                for (int grp = 0; grp < 4; ++grp) {
                    const float4 fa = *reinterpret_cast<const float4*>(gp + grp * 8);
                    const float4 fb = *reinterpret_cast<const float4*>(gp + grp * 8 + 4);
                    const float x[8] = {fa.x, fa.y, fa.z, fa.w, fb.x, fb.y, fb.z, fb.w};
                    s16x8 hi, lo;
#pragma unroll
                    for (int i = 0; i < 8; ++i) {
                        const unsigned h = f2bf(x[i]);
                        hi[i] = (short)h;
                        lo[i] = (short)f2bf(x[i] - bf2f(h));
                    }
                    const unsigned off = (unsigned)srow * 128u +
                        (((unsigned)(shalf * 64 + grp * 16)) ^ swr);
                    *reinterpret_cast<s16x8*>(KhiB + off) = hi;
                    *reinterpret_cast<s16x8*>(KloB + off) = lo;
                }
                if (kt == 0 && tid < 128) {
                    const float* tp = tgt + ((size_t)b * N_ + m0 + tid) * 3;
                    Ts4[tid] = make_float4(tp[0], tp[1], tp[2], 0.f);
                }
            }
            __syncthreads();
#pragma unroll
            for (int ks = 0; ks < 2; ++ks) {
                const int s = kt * 2 + ks;
                const unsigned kb = ((unsigned)(lg * 16 + ks * 64)) ^ swl;
#pragma unroll
                for (int nf = 0; nf < 8; ++nf) {
                    const unsigned off = (unsigned)(nf * 16 + lr) * 128u + kb;
                    const s16x8 ah = *reinterpret_cast<const s16x8*>(KhiB + off);
                    const s16x8 al = *reinterpret_cast<const s16x8*>(KloB + off);
                    acc[nf] = __builtin_amdgcn_mfma_f32_16x16x32_bf16(ah, qhi[s], acc[nf], 0, 0, 0);
                    acc[nf] = __builtin_amdgcn_mfma_f32_16x16x32_bf16(al, qhi[s], acc[nf], 0, 0, 0);
                    acc[nf] = __builtin_amdgcn_mfma_f32_16x16x32_bf16(ah, qlo[s], acc[nf], 0, 0, 0);
                }
            }
        }

        float mx = -1e30f;
#pragma unroll
        for (int nf = 0; nf < 8; ++nf)
#pragma unroll
            for (int r = 0; r < 4; ++r) mx = fmaxf(mx, acc[nf][r]);
        mx = fmaxf(mx, __shfl_xor(mx, 16));
        mx = fmaxf(mx, __shfl_xor(mx, 32));

        const float mnew = fmaxf(m_run, mx);
        const float corr = __expf(m_run - mnew);
        l_run *= corr; a0 *= corr; a1 *= corr; a2 *= corr;

        float ps = 0.f, p0 = 0.f, p1 = 0.f, p2 = 0.f;
#pragma unroll
        for (int nf = 0; nf < 8; ++nf)
#pragma unroll
            for (int r = 0; r < 4; ++r) {
                const float p = __expf(acc[nf][r] - mnew);
                const int n = nf * 16 + lg * 4 + r;
                const float4 tv = Ts4[n];
                ps += p;
                p0 = fmaf(p, tv.x, p0);
                p1 = fmaf(p, tv.y, p1);
                p2 = fmaf(p, tv.z, p2);
            }
        l_run += ps; a0 += p0; a1 += p1; a2 += p2;
        m_run = mnew;
    }

    l_run += __shfl_xor(l_run, 16); l_run += __shfl_xor(l_run, 32);
    a0 += __shfl_xor(a0, 16); a0 += __shfl_xor(a0, 32);
    a1 += __shfl_xor(a1, 16); a1 += __shfl_xor(a1, 32);
    a2 += __shfl_xor(a2, 16); a2 += __shfl_xor(a2, 32);

    __syncthreads();
    if (lg == 0) {
        const float inv = 1.0f / l_run;
        const double mx0 = (double)(a0 * inv);
        const double mx1 = (double)(a1 * inv);
        const double mx2 = (double)(a2 * inv);
        const float* sp = src + ((size_t)b * N_ + qrow) * 3;
        const double s0 = sp[0], s1 = sp[1], s2 = sp[2];
        double* rp = red[wv * 16 + lr];
        rp[0] = s0;  rp[1] = s1;  rp[2] = s2;
        rp[3] = mx0; rp[4] = mx1; rp[5] = mx2;
        rp[6]  = s0 * mx0; rp[7]  = s0 * mx1; rp[8]  = s0 * mx2;
        rp[9]  = s1 * mx0; rp[10] = s1 * mx1; rp[11] = s1 * mx2;
        rp[12] = s2 * mx0; rp[13] = s2 * mx1; rp[14] = s2 * mx2;
    }
    __syncthreads();
    if (tid < 15) {
        double sum = 0.0;
        for (int j = 0; j < 64; ++j) sum += red[j][tid];
        partials[(size_t)blk * 15 + tid] = (float)sum;
    }
}

// ---------------------------------------------------------------------------
// Kabsch (fp64 internals, float partials), nbb = partial blocks per batch.
// ---------------------------------------------------------------------------
__global__ void kabsch_kernel(const float* __restrict__ partials,
                              float* __restrict__ out, int nbb)
{
    const int b = threadIdx.x;
    if (b >= B_) return;

    double acc[15];
#pragma unroll
    for (int i = 0; i < 15; ++i) acc[i] = 0.0;
    for (int rb = 0; rb < nbb; ++rb) {
        const float* p = partials + ((size_t)b * nbb + rb) * 15;
#pragma unroll
        for (int i = 0; i < 15; ++i) acc[i] += (double)p[i];
    }

    const double invN = 1.0 / (double)N_;
    const double S[3] = {acc[0], acc[1], acc[2]};
    const double M[3] = {acc[3], acc[4], acc[5]};
    double H[3][3];
    for (int c = 0; c < 3; ++c)
        for (int d = 0; d < 3; ++d)
            H[c][d] = acc[6 + c * 3 + d] - S[c] * M[d] * invN;

    double A[3][3];
    for (int i = 0; i < 3; ++i)
        for (int j = 0; j < 3; ++j)
            A[i][j] = H[0][i] * H[0][j] + H[1][i] * H[1][j] + H[2][i] * H[2][j];

    double V[3][3] = {{1, 0, 0}, {0, 1, 0}, {0, 0, 1}};
    const int PQ[3][2] = {{0, 1}, {0, 2}, {1, 2}};
    for (int sweep = 0; sweep < 20; ++sweep) {
        const double off = fabs(A[0][1]) + fabs(A[0][2]) + fabs(A[1][2]);
        if (off < 1e-24) break;
        for (int pi = 0; pi < 3; ++pi) {
            const int p = PQ[pi][0], q = PQ[pi][1], rr = 3 - p - q;
            const double apq = A[p][q];
            if (fabs(apq) < 1e-300) continue;
            const double theta = (A[q][q] - A[p][p]) / (2.0 * apq);
            const double tt = (theta >= 0.0 ? 1.0 : -1.0) /
                              (fabs(theta) + sqrt(1.0 + theta * theta));
            const double c = 1.0 / sqrt(1.0 + tt * tt);
            const double sn = tt * c;
            const double app = A[p][p], aqq = A[q][q];
            const double arp = A[rr][p], arq = A[rr][q];
            A[p][p] = app - tt * apq;
            A[q][q] = aqq + tt * apq;
            A[p][q] = A[q][p] = 0.0;
            A[rr][p] = A[p][rr] = c * arp - sn * arq;
            A[rr][q] = A[q][rr] = sn * arp + c * arq;
            for (int k = 0; k < 3; ++k) {
                const double vkp = V[k][p], vkq = V[k][q];
                V[k][p] = c * vkp - sn * vkq;
                V[k][q] = sn * vkp + c * vkq;
            }
        }
    }

    double R[3][3] = {{0, 0, 0}, {0, 0, 0}, {0, 0, 0}};
    for (int i = 0; i < 3; ++i) {
        const double lam = A[i][i];
        const double sig = sqrt(lam > 0.0 ? lam : 0.0);
        const double inv = 1.0 / (sig > 1e-30 ? sig : 1e-30);
        double wv[3];
        for (int c = 0; c < 3; ++c)
            wv[c] = H[c][0] * V[0][i] + H[c][1] * V[1][i] + H[c][2] * V[2][i];
        for (int r = 0; r < 3; ++r)
            for (int c = 0; c < 3; ++c)
                R[r][c] += V[r][i] * wv[c] * inv;
    }

    const double det =
        R[0][0] * (R[1][1] * R[2][2] - R[1][2] * R[2][1]) -
        R[0][1] * (R[1][0] * R[2][2] - R[1][2] * R[2][0]) +
        R[0][2] * (R[1][0] * R[2][1] - R[1][1] * R[2][0]);
    if (det < 0.0) {
        R[2][0] = -R[2][0]; R[2][1] = -R[2][1]; R[2][2] = -R[2][2];
    }

    double t[3];
    for (int c = 0; c < 3; ++c)
        t[c] = M[c] * invN -
               (R[c][0] * S[0] + R[c][1] * S[1] + R[c][2] * S[2]) * invN;

    for (int r = 0; r < 3; ++r)
        for (int c = 0; c < 3; ++c)
            out[(size_t)b * 9 + r * 3 + c] = (float)R[r][c];
    for (int c = 0; c < 3; ++c)
        out[(size_t)B_ * 9 + (size_t)b * 3 + c] = (float)t[c];
}

// ---------------------------------------------------------------------------
extern "C" void kernel_launch(void* const* d_in, const int* in_sizes, int n_in,
                              void* d_out, int out_size, void* d_ws, size_t ws_size,
                              hipStream_t stream) {
    const float* src = (const float*)d_in[0];
    const float* tgt = (const float*)d_in[1];
    const float* se  = (const float*)d_in[2];
    const float* te  = (const float*)d_in[3];
    float* out = (float*)d_out;

    const size_t KP_OFF = 32768;   // float partials: 512*15*4 = 30720 B
    const size_t need = KP_OFF + (size_t)B_ * N_ * D_ * 2;  // 67,141,632 B

    if (ws_size >= need) {
        u32x4* kp = (u32x4*)((char*)d_ws + KP_OFF);
        prepass_kernel<<<dim3(16384), dim3(256), 0, stream>>>(te, kp);
        attn_db_kernel<<<dim3(512), dim3(NT), 0, stream>>>(
            src, tgt, se, kp, (float*)d_ws);
        kabsch_kernel<<<dim3(1), dim3(64), 0, stream>>>((float*)d_ws, out, 16);
    } else {
        attn_v2_kernel<<<dim3(1024), dim3(256), 0, stream>>>(
            src, tgt, se, te, (float*)d_ws);
        kabsch_kernel<<<dim3(1), dim3(64), 0, stream>>>((float*)d_ws, out, 32);
    }
}